// Round 3
// baseline (6446.436 us; speedup 1.0000x reference)
//
#include <hip/hip_runtime.h>

// D-MPNN (chemprop) x3 encoders on MI355X.
// Algebra: h_nei@Ur == (h@Ur)[bgraph]; hmess@W hoisted (zpre/hpre/r1b).
// R1: split latency-bound gather from MFMA GEMM; sums alias the HBout buffer.
// R2: resubmit after infra flake; removed readfirstlane (uniform anyway).

#define NE 100000   // messages
#define NN 50000    // nodes

typedef unsigned short u16;
typedef short short8 __attribute__((ext_vector_type(8)));
typedef float f32x4 __attribute__((ext_vector_type(4)));
typedef unsigned short u16x4 __attribute__((ext_vector_type(4)));

__device__ __forceinline__ float b2f(u16 u) {
  union { unsigned int i; float f; } v; v.i = ((unsigned int)u) << 16; return v.f;
}
__device__ __forceinline__ u16 f2b(float f) {
  union { float f; unsigned int i; } v; v.f = f;
  unsigned int b = v.i;
  b += 0x7FFFu + ((b >> 16) & 1u);   // RTNE
  return (u16)(b >> 16);
}
__device__ __forceinline__ float sigm(float x) { return 1.0f / (1.0f + __expf(-x)); }
__device__ __forceinline__ float tanh_f(float x) { return 2.0f / (1.0f + __expf(-2.0f * x)) - 1.0f; }
__device__ __forceinline__ f32x4 mfma16(short8 a, short8 b, f32x4 c) {
  return __builtin_amdgcn_mfma_f32_16x16x32_bf16(a, b, c, 0, 0, 0);
}

// ---------------- weight packing (fragment-major) ----------------
// elem j of lane l at ((s*NB16+nb)*64+l)*8+j holds W[32*s+8*(l>>4)+j][16*nb+(l&15)]

__global__ void pack_wpre(const float* __restrict__ Wr, const float* __restrict__ Wz,
                          const float* __restrict__ Wh, u16* __restrict__ dst) {
  const int g = blockIdx.y;
  const int p = blockIdx.x * 256 + threadIdx.x;           // < 98304  (K=128,N=768)
  const int j = p & 7, l = (p >> 3) & 63, q = p >> 9;
  const int nb = q % 48, s = q / 48;
  const int k = 32 * s + 8 * (l >> 4) + j;
  const int n = 16 * nb + (l & 15);
  float v = 0.f;
  if (k < 104) {
    if (n < 256)      v = Wr[((size_t)g * 104 + k) * 256 + n];
    else if (n < 512) v = Wz[((size_t)g * 360 + k) * 256 + (n - 256)];
    else              v = Wh[((size_t)g * 360 + k) * 256 + (n - 512)];
  }
  dst[(size_t)g * 98304 + p] = f2b(v);
}

__global__ void pack_wgate(const float* __restrict__ Wz, const float* __restrict__ Wh,
                           u16* __restrict__ dst) {
  const int g = blockIdx.y;
  const int p = blockIdx.x * 256 + threadIdx.x;           // < 131072 (K=256,N=512)
  const int j = p & 7, l = (p >> 3) & 63, q = p >> 9;
  const int nb = q % 32, s = q / 32;
  const int k = 32 * s + 8 * (l >> 4) + j;
  const int n = 16 * nb + (l & 15);
  float v = (n < 256) ? Wz[((size_t)g * 360 + 104 + k) * 256 + n]
                      : Wh[((size_t)g * 360 + 104 + k) * 256 + (n - 256)];
  dst[(size_t)g * 131072 + p] = f2b(v);
}

__global__ void pack_ur(const float* __restrict__ Ur, u16* __restrict__ dst) {
  const int g = blockIdx.y;
  const int p = blockIdx.x * 256 + threadIdx.x;           // < 65536 (K=256,N=256)
  const int j = p & 7, l = (p >> 3) & 63, q = p >> 9;
  const int nb = q % 16, s = q / 16;
  const int k = 32 * s + 8 * (l >> 4) + j;
  const int n = 16 * nb + (l & 15);
  dst[(size_t)g * 65536 + p] = f2b(Ur[((size_t)g * 256 + k) * 256 + n]);
}

__global__ void pack_wo(const float* __restrict__ Wo, u16* __restrict__ dst) {
  const int g = blockIdx.y;
  const int p = blockIdx.x * 256 + threadIdx.x;           // < 98304 (K=384,N=256)
  const int j = p & 7, l = (p >> 3) & 63, q = p >> 9;
  const int nb = q % 16, s = q / 16;
  const int k = 32 * s + 8 * (l >> 4) + j;
  const int n = 16 * nb + (l & 15);
  float v = 0.f;
  if (k < 98)        v = Wo[((size_t)g * 354 + k) * 256 + n];        // fnode part
  else if (k >= 128) v = Wo[((size_t)g * 354 + (k - 30)) * 256 + n]; // nei part
  dst[(size_t)g * 98304 + p] = f2b(v);
}

// ---------------- embeddings ----------------
__global__ void embed_hmess(const float* __restrict__ fnode, const int* __restrict__ fmess_idx,
                            const float* __restrict__ fmess_feat, u16* __restrict__ hmess) {
  const int e = blockIdx.x * 2 + (threadIdx.x >> 7);
  const int c = threadIdx.x & 127;
  const int src = fmess_idx[e * 2];
  float v = 0.f;
  if (c < 98)       v = fnode[(size_t)src * 98 + c];
  else if (c < 104) v = fmess_feat[(size_t)e * 6 + (c - 98)];
  hmess[(size_t)e * 128 + c] = f2b(v);
}

__global__ void embed_fnode(const float* __restrict__ fnode, u16* __restrict__ fnp) {
  const int n = blockIdx.x * 2 + (threadIdx.x >> 7);
  const int c = threadIdx.x & 127;
  float v = (c < 98) ? fnode[(size_t)n * 98 + c] : 0.f;
  fnp[(size_t)n * 128 + c] = f2b(v);
}

// ---------------- pre-GEMM: pre[E][768] = hmess[E][128] @ Wpre + bias ----------------
__global__ __launch_bounds__(256)
void pre_gemm(const u16* __restrict__ hmess, const u16* __restrict__ Wpre,
              const float* __restrict__ bur, const float* __restrict__ bz,
              const float* __restrict__ bh, u16* __restrict__ pre) {
  const int tid = threadIdx.x, wave = tid >> 6, lane = tid & 63;
  const int e0 = blockIdx.x * 32;
  const int cchunk = blockIdx.y;
  const int row0 = lane & 15, kq = lane >> 4;
  f32x4 acc[2][4];
#pragma unroll
  for (int i = 0; i < 2; ++i)
#pragma unroll
    for (int n = 0; n < 4; ++n) { acc[i][n][0]=0.f; acc[i][n][1]=0.f; acc[i][n][2]=0.f; acc[i][n][3]=0.f; }
#pragma unroll
  for (int s = 0; s < 4; ++s) {
    short8 a0 = *(const short8*)(hmess + (size_t)(e0 + row0) * 128 + s * 32 + kq * 8);
    short8 a1 = *(const short8*)(hmess + (size_t)(e0 + 16 + row0) * 128 + s * 32 + kq * 8);
#pragma unroll
    for (int ni = 0; ni < 4; ++ni) {
      const int nb = cchunk * 16 + wave * 4 + ni;
      short8 b = *(const short8*)(Wpre + ((size_t)(s * 48 + nb) * 64 + lane) * 8);
      acc[0][ni] = mfma16(a0, b, acc[0][ni]);
      acc[1][ni] = mfma16(a1, b, acc[1][ni]);
    }
  }
  const float* bias = (cchunk == 0) ? bur : (cchunk == 1 ? bz : bh);
#pragma unroll
  for (int mi = 0; mi < 2; ++mi)
#pragma unroll
    for (int ni = 0; ni < 4; ++ni)
#pragma unroll
      for (int v = 0; v < 4; ++v) {
        const int m = mi * 16 + kq * 4 + v;
        const int col = cchunk * 256 + wave * 64 + ni * 16 + row0;
        const int e = e0 + m;
        pre[(size_t)e * 768 + col] = f2b(acc[mi][ni][v] + bias[col & 255]);
      }
}

// ---------------- gather: SG[e] = (sum_h | sum_gh), barrier-free, 2 msgs/wave ----------------
__global__ __launch_bounds__(256)
void gather_sums(const u16* __restrict__ HBin, u16* __restrict__ SG,
                 const u16* __restrict__ pre, const int* __restrict__ bgraph) {
  const int lane = threadIdx.x & 63;
  const int wid = (int)((blockIdx.x * 256 + threadIdx.x) >> 6);   // wave-uniform

  int idx[2][6];
#pragma unroll
  for (int m = 0; m < 2; ++m)
#pragma unroll
    for (int k = 0; k < 6; ++k)
      idx[m][k] = bgraph[(wid * 2 + m) * 6 + k];

  float r1f[2][4];
#pragma unroll
  for (int m = 0; m < 2; ++m) {
    const u16x4 r1v = *(const u16x4*)(pre + (size_t)(wid * 2 + m) * 768 + 4 * lane);
#pragma unroll
    for (int j = 0; j < 4; ++j) r1f[m][j] = b2f(r1v[j]);
  }

  u16x4 hv[2][6], huv[2][6];
#pragma unroll
  for (int m = 0; m < 2; ++m)
#pragma unroll
    for (int k = 0; k < 6; ++k) {
      const u16* row = HBin + (size_t)idx[m][k] * 512;
      hv[m][k]  = *(const u16x4*)(row + 4 * lane);
      huv[m][k] = *(const u16x4*)(row + 256 + 4 * lane);
    }

#pragma unroll
  for (int m = 0; m < 2; ++m) {
    float sh[4] = {0.f, 0.f, 0.f, 0.f}, sg[4] = {0.f, 0.f, 0.f, 0.f};
#pragma unroll
    for (int k = 0; k < 6; ++k)
#pragma unroll
      for (int j = 0; j < 4; ++j) {
        const float h  = b2f(hv[m][k][j]);
        const float rg = sigm(r1f[m][j] + b2f(huv[m][k][j]));
        sh[j] += h;
        sg[j] += rg * h;
      }
    u16x4 o0, o1;
#pragma unroll
    for (int j = 0; j < 4; ++j) { o0[j] = f2b(sh[j]); o1[j] = f2b(sg[j]); }
    *(u16x4*)(SG + (size_t)(wid * 2 + m) * 512 + 4 * lane) = o0;
    *(u16x4*)(SG + (size_t)(wid * 2 + m) * 512 + 256 + 4 * lane) = o1;
  }
}

// ---------------- GRU GEMM: HB holds (sh|sg) on entry, (h|hu) on exit ----------------
__global__ __launch_bounds__(256)
void gru_gemm(u16* __restrict__ HB, const u16* __restrict__ pre,
              const u16* __restrict__ Wgate, const u16* __restrict__ Urp) {
  __shared__ __align__(16) u16 sH[32][264];
  const int tid = threadIdx.x, wave = tid >> 6, lane = tid & 63;
  const int e0 = blockIdx.x * 32;
  const int row0 = lane & 15, kq = lane >> 4;

  f32x4 accZ[2][4], accH[2][4];
#pragma unroll
  for (int i = 0; i < 2; ++i)
#pragma unroll
    for (int n = 0; n < 4; ++n) {
      accZ[i][n][0]=0.f; accZ[i][n][1]=0.f; accZ[i][n][2]=0.f; accZ[i][n][3]=0.f;
      accH[i][n][0]=0.f; accH[i][n][1]=0.f; accH[i][n][2]=0.f; accH[i][n][3]=0.f;
    }

  // gate GEMMs: gz = sh @ Wz2, gh = sg @ Wh2.  A straight from global (rows e0..e0+31).
#pragma unroll
  for (int s = 0; s < 8; ++s) {
    const u16* r0 = HB + (size_t)(e0 + row0) * 512 + s * 32 + kq * 8;
    const u16* r1 = HB + (size_t)(e0 + 16 + row0) * 512 + s * 32 + kq * 8;
    short8 ah0 = *(const short8*)(r0);
    short8 ah1 = *(const short8*)(r1);
    short8 ag0 = *(const short8*)(r0 + 256);
    short8 ag1 = *(const short8*)(r1 + 256);
#pragma unroll
    for (int ni = 0; ni < 4; ++ni) {
      const int nbz = wave * 4 + ni;
      short8 bz_ = *(const short8*)(Wgate + ((size_t)(s * 32 + nbz) * 64 + lane) * 8);
      short8 bh_ = *(const short8*)(Wgate + ((size_t)(s * 32 + 16 + nbz) * 64 + lane) * 8);
      accZ[0][ni] = mfma16(ah0, bz_, accZ[0][ni]);
      accZ[1][ni] = mfma16(ah1, bz_, accZ[1][ni]);
      accH[0][ni] = mfma16(ag0, bh_, accH[0][ni]);
      accH[1][ni] = mfma16(ag1, bh_, accH[1][ni]);
    }
  }
  __syncthreads();   // all sh/sg reads complete (MFMA data-deps) before in-place overwrite

  // GRU epilogue: hnew in place of sh; stash to LDS for Ur GEMM
#pragma unroll
  for (int mi = 0; mi < 2; ++mi)
#pragma unroll
    for (int ni = 0; ni < 4; ++ni)
#pragma unroll
      for (int v = 0; v < 4; ++v) {
        const int m = mi * 16 + kq * 4 + v;
        const int col = wave * 64 + ni * 16 + row0;
        const int e = e0 + m;
        const float zp = b2f(pre[(size_t)e * 768 + 256 + col]);
        const float hp = b2f(pre[(size_t)e * 768 + 512 + col]);
        const float z  = sigm(zp + accZ[mi][ni][v]);
        const float ph = tanh_f(hp + accH[mi][ni][v]);
        const float shv = b2f(HB[(size_t)e * 512 + col]);
        float hn = (1.0f - z) * shv + z * ph;
        if (e == 0) hn = 0.f;                 // e_mask
        const u16 hb = f2b(hn);
        HB[(size_t)e * 512 + col] = hb;
        sH[m][col] = hb;
      }
  __syncthreads();

  // hu = hnew @ Ur  (overwrites sg half, which is dead)
  f32x4 accU[2][4];
#pragma unroll
  for (int i = 0; i < 2; ++i)
#pragma unroll
    for (int n = 0; n < 4; ++n) { accU[i][n][0]=0.f; accU[i][n][1]=0.f; accU[i][n][2]=0.f; accU[i][n][3]=0.f; }
#pragma unroll
  for (int s = 0; s < 8; ++s) {
    short8 a0 = *(const short8*)&sH[row0][s * 32 + kq * 8];
    short8 a1 = *(const short8*)&sH[row0 + 16][s * 32 + kq * 8];
#pragma unroll
    for (int ni = 0; ni < 4; ++ni) {
      short8 b = *(const short8*)(Urp + ((size_t)(s * 16 + wave * 4 + ni) * 64 + lane) * 8);
      accU[0][ni] = mfma16(a0, b, accU[0][ni]);
      accU[1][ni] = mfma16(a1, b, accU[1][ni]);
    }
  }
#pragma unroll
  for (int mi = 0; mi < 2; ++mi)
#pragma unroll
    for (int ni = 0; ni < 4; ++ni)
#pragma unroll
      for (int v = 0; v < 4; ++v) {
        const int m = mi * 16 + kq * 4 + v;
        const int col = wave * 64 + ni * 16 + row0;
        const int e = e0 + m;
        HB[(size_t)e * 512 + 256 + col] = f2b(accU[mi][ni][v]);
      }
}

// ---------------- depth-0: hn = sigm(zpre)*tanh(hpre); hu = hn @ Ur ----------------
__global__ __launch_bounds__(256)
void step0(u16* __restrict__ HB, const u16* __restrict__ pre, const u16* __restrict__ Urp) {
  __shared__ __align__(16) u16 sH[32][264];
  const int tid = threadIdx.x, wave = tid >> 6, lane = tid & 63;
  const int e0 = blockIdx.x * 32;
  const int row0 = lane & 15, kq = lane >> 4;
#pragma unroll
  for (int mi = 0; mi < 2; ++mi)
#pragma unroll
    for (int ni = 0; ni < 4; ++ni)
#pragma unroll
      for (int v = 0; v < 4; ++v) {
        const int m = mi * 16 + kq * 4 + v;
        const int col = wave * 64 + ni * 16 + row0;
        const int e = e0 + m;
        const float zp = b2f(pre[(size_t)e * 768 + 256 + col]);
        const float hp = b2f(pre[(size_t)e * 768 + 512 + col]);
        float hn = sigm(zp) * tanh_f(hp);
        if (e == 0) hn = 0.f;
        const u16 hb = f2b(hn);
        HB[(size_t)e * 512 + col] = hb;
        sH[m][col] = hb;
      }
  __syncthreads();
  f32x4 accU[2][4];
#pragma unroll
  for (int i = 0; i < 2; ++i)
#pragma unroll
    for (int n = 0; n < 4; ++n) { accU[i][n][0]=0.f; accU[i][n][1]=0.f; accU[i][n][2]=0.f; accU[i][n][3]=0.f; }
#pragma unroll
  for (int s = 0; s < 8; ++s) {
    short8 a0 = *(const short8*)&sH[row0][s * 32 + kq * 8];
    short8 a1 = *(const short8*)&sH[row0 + 16][s * 32 + kq * 8];
#pragma unroll
    for (int ni = 0; ni < 4; ++ni) {
      short8 b = *(const short8*)(Urp + ((size_t)(s * 16 + wave * 4 + ni) * 64 + lane) * 8);
      accU[0][ni] = mfma16(a0, b, accU[0][ni]);
      accU[1][ni] = mfma16(a1, b, accU[1][ni]);
    }
  }
#pragma unroll
  for (int mi = 0; mi < 2; ++mi)
#pragma unroll
    for (int ni = 0; ni < 4; ++ni)
#pragma unroll
      for (int v = 0; v < 4; ++v) {
        const int m = mi * 16 + kq * 4 + v;
        const int col = wave * 64 + ni * 16 + row0;
        const int e = e0 + m;
        HB[(size_t)e * 512 + 256 + col] = f2b(accU[mi][ni][v]);
      }
}

// ---------------- readout ----------------
__global__ __launch_bounds__(256)
void readout(const u16* __restrict__ HB, const u16* __restrict__ fnp,
             const int* __restrict__ agraph, const u16* __restrict__ Wop,
             const float* __restrict__ bo, float* __restrict__ out) {
  __shared__ __align__(16) u16 sN[32][264];
  const int tid = threadIdx.x, wave = tid >> 6, lane = tid & 63;
  const int n0 = blockIdx.x * 32;
  const int row0 = lane & 15, kq = lane >> 4;

#pragma unroll 2
  for (int rr = 0; rr < 8; ++rr) {
    const int r = wave * 8 + rr;
    const int n = n0 + r;
    float s4[4] = {0.f, 0.f, 0.f, 0.f};
    if (n < NN) {
#pragma unroll
      for (int k = 0; k < 6; ++k) {
        const int idx = agraph[n * 6 + k];
        const u16x4 hv = *(const u16x4*)(HB + (size_t)idx * 512 + 4 * lane);
#pragma unroll
        for (int j = 0; j < 4; ++j) s4[j] += b2f(hv[j]);
      }
    }
#pragma unroll
    for (int j = 0; j < 4; ++j) sN[r][4 * lane + j] = f2b(s4[j]);
  }
  __syncthreads();

  f32x4 acc[2][4];
#pragma unroll
  for (int i = 0; i < 2; ++i)
#pragma unroll
    for (int n = 0; n < 4; ++n) { acc[i][n][0]=0.f; acc[i][n][1]=0.f; acc[i][n][2]=0.f; acc[i][n][3]=0.f; }
  const int ra = min(n0 + row0, NN - 1);
  const int rb = min(n0 + 16 + row0, NN - 1);
#pragma unroll
  for (int s = 0; s < 12; ++s) {
    short8 a0, a1;
    if (s < 4) {
      a0 = *(const short8*)(fnp + (size_t)ra * 128 + s * 32 + kq * 8);
      a1 = *(const short8*)(fnp + (size_t)rb * 128 + s * 32 + kq * 8);
    } else {
      a0 = *(const short8*)&sN[row0][(s - 4) * 32 + kq * 8];
      a1 = *(const short8*)&sN[row0 + 16][(s - 4) * 32 + kq * 8];
    }
#pragma unroll
    for (int ni = 0; ni < 4; ++ni) {
      short8 b = *(const short8*)(Wop + ((size_t)(s * 16 + wave * 4 + ni) * 64 + lane) * 8);
      acc[0][ni] = mfma16(a0, b, acc[0][ni]);
      acc[1][ni] = mfma16(a1, b, acc[1][ni]);
    }
  }
#pragma unroll
  for (int mi = 0; mi < 2; ++mi)
#pragma unroll
    for (int ni = 0; ni < 4; ++ni)
#pragma unroll
      for (int v = 0; v < 4; ++v) {
        const int m = mi * 16 + kq * 4 + v;
        const int col = wave * 64 + ni * 16 + row0;
        const int n = n0 + m;
        if (n < NN) {
          float val = fmaxf(acc[mi][ni][v] + bo[col], 0.f);
          if (n == 0) val = 0.f;             // n_mask
          out[(size_t)n * 256 + col] = val;
        }
      }
}

extern "C" void kernel_launch(void* const* d_in, const int* in_sizes, int n_in,
                              void* d_out, int out_size, void* d_ws, size_t ws_size,
                              hipStream_t stream) {
  const float* fnode      = (const float*)d_in[0];
  const int*   fmess_idx  = (const int*)d_in[1];
  const float* fmess_feat = (const float*)d_in[2];
  const int*   agraph     = (const int*)d_in[3];
  const int*   bgraph     = (const int*)d_in[4];
  const float* Wz         = (const float*)d_in[5];
  const float* bz         = (const float*)d_in[6];
  const float* Wr         = (const float*)d_in[7];
  const float* Ur         = (const float*)d_in[8];
  const float* bur        = (const float*)d_in[9];
  const float* Wh         = (const float*)d_in[10];
  const float* bh         = (const float*)d_in[11];
  const float* Wo         = (const float*)d_in[12];
  const float* bo         = (const float*)d_in[13];
  float* out = (float*)d_out;

  char* ws = (char*)d_ws;
  size_t off = 0;
  auto carve = [&](size_t bytes) -> char* {
    char* p = ws + off;
    off += (bytes + 511) & ~(size_t)511;
    return p;
  };
  u16* HB0   = (u16*)carve((size_t)NE * 512 * 2);
  u16* HB1   = (u16*)carve((size_t)NE * 512 * 2);
  u16* pre   = (u16*)carve((size_t)NE * 768 * 2);
  u16* hmess = (u16*)carve((size_t)NE * 128 * 2);
  u16* fnp   = (u16*)carve((size_t)NN * 128 * 2);
  u16* wpre  = (u16*)carve((size_t)3 * 98304 * 2);
  u16* wgate = (u16*)carve((size_t)3 * 131072 * 2);
  u16* urp   = (u16*)carve((size_t)3 * 65536 * 2);
  u16* wop   = (u16*)carve((size_t)3 * 98304 * 2);
  if (off > ws_size) return;

  pack_wpre <<<dim3(384, 3), 256, 0, stream>>>(Wr, Wz, Wh, wpre);
  pack_wgate<<<dim3(512, 3), 256, 0, stream>>>(Wz, Wh, wgate);
  pack_ur   <<<dim3(256, 3), 256, 0, stream>>>(Ur, urp);
  pack_wo   <<<dim3(384, 3), 256, 0, stream>>>(Wo, wop);
  embed_hmess<<<NE / 2, 256, 0, stream>>>(fnode, fmess_idx, fmess_feat, hmess);
  embed_fnode<<<NN / 2, 256, 0, stream>>>(fnode, fnp);

  for (int g = 0; g < 3; ++g) {
    pre_gemm<<<dim3(NE / 32, 3), 256, 0, stream>>>(
        hmess, wpre + (size_t)g * 98304, bur + g * 256, bz + g * 256, bh + g * 256, pre);
    const u16* wgate_g = wgate + (size_t)g * 131072;
    const u16* urp_g   = urp + (size_t)g * 65536;
    step0<<<NE / 32, 256, 0, stream>>>(HB0, pre, urp_g);
    u16* bufs[2] = {HB0, HB1};
    int cur = 0;
    for (int d = 1; d < 6; ++d) {
      gather_sums<<<NE / 8, 256, 0, stream>>>(bufs[cur], bufs[1 - cur], pre, bgraph);
      gru_gemm<<<NE / 32, 256, 0, stream>>>(bufs[1 - cur], pre, wgate_g, urp_g);
      cur ^= 1;
    }
    readout<<<(NN + 31) / 32, 256, 0, stream>>>(
        bufs[cur], fnp, agraph, wop + (size_t)g * 98304, bo + g * 256, out + (size_t)g * NN * 256);
  }
}

// Round 4
// 6190.574 us; speedup vs baseline: 1.0413x; 1.0413x over previous
//
#include <hip/hip_runtime.h>

// D-MPNN (chemprop) x3 encoders on MI355X.
// Algebra: h_nei@Ur == (h@Ur)[bgraph]; hmess@W hoisted (zpre/hpre/r1b).
// R3: transposed-operand gru_step (D[n][e]); gather writes sums in MFMA
//     B-frag layout -> vectorized epilogue, W-frag reuse x8, 128-row blocks.

#define NE 100000   // messages
#define NEP 100096  // padded to 128-row blocks
#define NN 50000    // nodes

typedef unsigned short u16;
typedef short short8 __attribute__((ext_vector_type(8)));
typedef float f32x4 __attribute__((ext_vector_type(4)));
typedef unsigned short u16x4 __attribute__((ext_vector_type(4)));

__device__ __forceinline__ float b2f(u16 u) {
  union { unsigned int i; float f; } v; v.i = ((unsigned int)u) << 16; return v.f;
}
__device__ __forceinline__ u16 f2b(float f) {
  union { float f; unsigned int i; } v; v.f = f;
  unsigned int b = v.i;
  b += 0x7FFFu + ((b >> 16) & 1u);   // RTNE
  return (u16)(b >> 16);
}
__device__ __forceinline__ float sigm(float x) { return 1.0f / (1.0f + __expf(-x)); }
__device__ __forceinline__ float tanh_f(float x) { return 2.0f / (1.0f + __expf(-2.0f * x)) - 1.0f; }
__device__ __forceinline__ f32x4 mfma16(short8 a, short8 b, f32x4 c) {
  return __builtin_amdgcn_mfma_f32_16x16x32_bf16(a, b, c, 0, 0, 0);
}

// ---------------- weight packing (fragment-major) ----------------
// elem j of lane l at ((s*NB16+nb)*64+l)*8+j holds W[32*s+8*(l>>4)+j][16*nb+(l&15)]
// Works as either MFMA operand (A/B frag layouts are index-identical on gfx950).

__global__ void pack_wpre(const float* __restrict__ Wr, const float* __restrict__ Wz,
                          const float* __restrict__ Wh, u16* __restrict__ dst) {
  const int g = blockIdx.y;
  const int p = blockIdx.x * 256 + threadIdx.x;           // < 98304  (K=128,N=768)
  const int j = p & 7, l = (p >> 3) & 63, q = p >> 9;
  const int nb = q % 48, s = q / 48;
  const int k = 32 * s + 8 * (l >> 4) + j;
  const int n = 16 * nb + (l & 15);
  float v = 0.f;
  if (k < 104) {
    if (n < 256)      v = Wr[((size_t)g * 104 + k) * 256 + n];
    else if (n < 512) v = Wz[((size_t)g * 360 + k) * 256 + (n - 256)];
    else              v = Wh[((size_t)g * 360 + k) * 256 + (n - 512)];
  }
  dst[(size_t)g * 98304 + p] = f2b(v);
}

__global__ void pack_wgate(const float* __restrict__ Wz, const float* __restrict__ Wh,
                           u16* __restrict__ dst) {
  const int g = blockIdx.y;
  const int p = blockIdx.x * 256 + threadIdx.x;           // < 131072 (K=256,N=512)
  const int j = p & 7, l = (p >> 3) & 63, q = p >> 9;
  const int nb = q % 32, s = q / 32;
  const int k = 32 * s + 8 * (l >> 4) + j;
  const int n = 16 * nb + (l & 15);
  float v = (n < 256) ? Wz[((size_t)g * 360 + 104 + k) * 256 + n]
                      : Wh[((size_t)g * 360 + 104 + k) * 256 + (n - 256)];
  dst[(size_t)g * 131072 + p] = f2b(v);
}

__global__ void pack_ur(const float* __restrict__ Ur, u16* __restrict__ dst) {
  const int g = blockIdx.y;
  const int p = blockIdx.x * 256 + threadIdx.x;           // < 65536 (K=256,N=256)
  const int j = p & 7, l = (p >> 3) & 63, q = p >> 9;
  const int nb = q % 16, s = q / 16;
  const int k = 32 * s + 8 * (l >> 4) + j;
  const int n = 16 * nb + (l & 15);
  dst[(size_t)g * 65536 + p] = f2b(Ur[((size_t)g * 256 + k) * 256 + n]);
}

__global__ void pack_wo(const float* __restrict__ Wo, u16* __restrict__ dst) {
  const int g = blockIdx.y;
  const int p = blockIdx.x * 256 + threadIdx.x;           // < 98304 (K=384,N=256)
  const int j = p & 7, l = (p >> 3) & 63, q = p >> 9;
  const int nb = q % 16, s = q / 16;
  const int k = 32 * s + 8 * (l >> 4) + j;
  const int n = 16 * nb + (l & 15);
  float v = 0.f;
  if (k < 98)        v = Wo[((size_t)g * 354 + k) * 256 + n];        // fnode part
  else if (k >= 128) v = Wo[((size_t)g * 354 + (k - 30)) * 256 + n]; // nei part
  dst[(size_t)g * 98304 + p] = f2b(v);
}

// ---------------- embeddings ----------------
__global__ void embed_hmess(const float* __restrict__ fnode, const int* __restrict__ fmess_idx,
                            const float* __restrict__ fmess_feat, u16* __restrict__ hmess) {
  const int e = blockIdx.x * 2 + (threadIdx.x >> 7);
  const int c = threadIdx.x & 127;
  const int src = fmess_idx[e * 2];
  float v = 0.f;
  if (c < 98)       v = fnode[(size_t)src * 98 + c];
  else if (c < 104) v = fmess_feat[(size_t)e * 6 + (c - 98)];
  hmess[(size_t)e * 128 + c] = f2b(v);
}

__global__ void embed_fnode(const float* __restrict__ fnode, u16* __restrict__ fnp) {
  const int n = blockIdx.x * 2 + (threadIdx.x >> 7);
  const int c = threadIdx.x & 127;
  float v = (c < 98) ? fnode[(size_t)n * 98 + c] : 0.f;
  fnp[(size_t)n * 128 + c] = f2b(v);
}

// ---------------- pre-GEMM: pre[E][768] = hmess[E][128] @ Wpre + bias ----------------
__global__ __launch_bounds__(256)
void pre_gemm(const u16* __restrict__ hmess, const u16* __restrict__ Wpre,
              const float* __restrict__ bur, const float* __restrict__ bz,
              const float* __restrict__ bh, u16* __restrict__ pre) {
  const int tid = threadIdx.x, wave = tid >> 6, lane = tid & 63;
  const int e0 = blockIdx.x * 32;
  const int cchunk = blockIdx.y;
  const int row0 = lane & 15, kq = lane >> 4;
  f32x4 acc[2][4];
#pragma unroll
  for (int i = 0; i < 2; ++i)
#pragma unroll
    for (int n = 0; n < 4; ++n) { acc[i][n][0]=0.f; acc[i][n][1]=0.f; acc[i][n][2]=0.f; acc[i][n][3]=0.f; }
#pragma unroll
  for (int s = 0; s < 4; ++s) {
    short8 a0 = *(const short8*)(hmess + (size_t)(e0 + row0) * 128 + s * 32 + kq * 8);
    short8 a1 = *(const short8*)(hmess + (size_t)(e0 + 16 + row0) * 128 + s * 32 + kq * 8);
#pragma unroll
    for (int ni = 0; ni < 4; ++ni) {
      const int nb = cchunk * 16 + wave * 4 + ni;
      short8 b = *(const short8*)(Wpre + ((size_t)(s * 48 + nb) * 64 + lane) * 8);
      acc[0][ni] = mfma16(a0, b, acc[0][ni]);
      acc[1][ni] = mfma16(a1, b, acc[1][ni]);
    }
  }
  const float* bias = (cchunk == 0) ? bur : (cchunk == 1 ? bz : bh);
#pragma unroll
  for (int mi = 0; mi < 2; ++mi)
#pragma unroll
    for (int ni = 0; ni < 4; ++ni)
#pragma unroll
      for (int v = 0; v < 4; ++v) {
        const int m = mi * 16 + kq * 4 + v;
        const int col = cchunk * 256 + wave * 64 + ni * 16 + row0;
        const int e = e0 + m;
        pre[(size_t)e * 768 + col] = f2b(acc[mi][ni][v] + bias[col & 255]);
      }
}

// ---------------- gather: writes (sum_h|sum_gh) in MFMA B-frag layout ----------------
// frag addr for value (E, C): (E>>4)*8192 + ((C>>5)*64 + (E&15) + 16*((C>>3)&3))*8 + (C&7)
// (sh at s-chunks 0..7, sg at 8..15)
__global__ __launch_bounds__(256)
void gather_sums(const u16* __restrict__ HBin, u16* __restrict__ SG,
                 const u16* __restrict__ pre, const int* __restrict__ bgraph) {
  const int lane = threadIdx.x & 63;
  const int wid = (int)((blockIdx.x * 256 + threadIdx.x) >> 6);   // wave-uniform

  int idx[2][6];
#pragma unroll
  for (int m = 0; m < 2; ++m)
#pragma unroll
    for (int k = 0; k < 6; ++k)
      idx[m][k] = bgraph[(wid * 2 + m) * 6 + k];

  float r1f[2][4];
#pragma unroll
  for (int m = 0; m < 2; ++m) {
    const u16x4 r1v = *(const u16x4*)(pre + (size_t)(wid * 2 + m) * 768 + 4 * lane);
#pragma unroll
    for (int j = 0; j < 4; ++j) r1f[m][j] = b2f(r1v[j]);
  }

  u16x4 hv[2][6], huv[2][6];
#pragma unroll
  for (int m = 0; m < 2; ++m)
#pragma unroll
    for (int k = 0; k < 6; ++k) {
      const u16* row = HBin + (size_t)idx[m][k] * 512;
      hv[m][k]  = *(const u16x4*)(row + 4 * lane);
      huv[m][k] = *(const u16x4*)(row + 256 + 4 * lane);
    }

#pragma unroll
  for (int m = 0; m < 2; ++m) {
    const int e = wid * 2 + m;
    float sh[4] = {0.f, 0.f, 0.f, 0.f}, sg[4] = {0.f, 0.f, 0.f, 0.f};
#pragma unroll
    for (int k = 0; k < 6; ++k)
#pragma unroll
      for (int j = 0; j < 4; ++j) {
        const float h  = b2f(hv[m][k][j]);
        const float rg = sigm(r1f[m][j] + b2f(huv[m][k][j]));
        sh[j] += h;
        sg[j] += rg * h;
      }
    u16x4 o0, o1;
#pragma unroll
    for (int j = 0; j < 4; ++j) { o0[j] = f2b(sh[j]); o1[j] = f2b(sg[j]); }
    // lane holds cols C = 4*lane .. 4*lane+3
    const size_t gb = (size_t)(e >> 4) * 8192;
    const int lsh = (((lane >> 3) * 64) + (e & 15) + 16 * ((lane >> 1) & 3)) * 8 + 4 * (lane & 1);
    *(u16x4*)(SG + gb + lsh) = o0;          // sh: s = lane>>3
    *(u16x4*)(SG + gb + lsh + 4096) = o1;   // sg: s + 8
  }
}

// ---------------- GRU step (transposed): HB holds frag (sh|sg) on entry, natural (h|hu) on exit
// 8 waves: wave wn owns output n in [wn*32, wn*32+32); e-cols 0..127 of block.
__global__ __launch_bounds__(512, 2)
void gru_step(u16* __restrict__ HB, const u16* __restrict__ pre,
              const u16* __restrict__ Wgate, const u16* __restrict__ Urp) {
  __shared__ __align__(16) u16 sHn[32768];   // hnew in frag layout, 64KB
  const int tid = threadIdx.x;
  const int wn = tid >> 6, lane = tid & 63;
  const int row0 = lane & 15, kq = lane >> 4;
  const int e0 = blockIdx.x * 128;
  const u16* SGb = HB + (size_t)(e0 >> 4) * 8192;

  f32x4 aZ[2][8], aH[2][8];
#pragma unroll
  for (int nf = 0; nf < 2; ++nf)
#pragma unroll
    for (int ef = 0; ef < 8; ++ef) {
      aZ[nf][ef][0]=0.f; aZ[nf][ef][1]=0.f; aZ[nf][ef][2]=0.f; aZ[nf][ef][3]=0.f;
      aH[nf][ef][0]=0.f; aH[nf][ef][1]=0.f; aH[nf][ef][2]=0.f; aH[nf][ef][3]=0.f;
    }

  // gate GEMMs: gz^T = Wz2-frag x sh-frag, gh^T = Wh2-frag x sg-frag
#pragma unroll
  for (int kc = 0; kc < 8; ++kc) {
    short8 wz0 = *(const short8*)(Wgate + ((size_t)(kc * 32 + wn * 2 + 0) * 64 + lane) * 8);
    short8 wz1 = *(const short8*)(Wgate + ((size_t)(kc * 32 + wn * 2 + 1) * 64 + lane) * 8);
    short8 wh0 = *(const short8*)(Wgate + ((size_t)(kc * 32 + 16 + wn * 2 + 0) * 64 + lane) * 8);
    short8 wh1 = *(const short8*)(Wgate + ((size_t)(kc * 32 + 16 + wn * 2 + 1) * 64 + lane) * 8);
#pragma unroll
    for (int ef = 0; ef < 8; ++ef) {
      short8 bsh = *(const short8*)(SGb + (size_t)ef * 8192 + (size_t)(kc * 64 + lane) * 8);
      short8 bsg = *(const short8*)(SGb + (size_t)ef * 8192 + (size_t)((8 + kc) * 64 + lane) * 8);
      aZ[0][ef] = mfma16(wz0, bsh, aZ[0][ef]);
      aZ[1][ef] = mfma16(wz1, bsh, aZ[1][ef]);
      aH[0][ef] = mfma16(wh0, bsg, aH[0][ef]);
      aH[1][ef] = mfma16(wh1, bsg, aH[1][ef]);
    }
  }

  // prefetch sh quads needed by epilogue (frag layout, vectorized)
  u16x4 shq[2][8];
#pragma unroll
  for (int nf = 0; nf < 2; ++nf) {
    const int lp = row0 + 16 * (nf * 2 + (kq >> 1));
    const int jo = 4 * (kq & 1);
#pragma unroll
    for (int ef = 0; ef < 8; ++ef)
      shq[nf][ef] = *(const u16x4*)(SGb + (size_t)ef * 8192 + (size_t)(wn * 64 + lp) * 8 + jo);
  }
  __syncthreads();   // drains all SG reads (vmcnt 0) in every wave before in-place overwrite

  // GRU epilogue: h natural write + hnew into LDS frag layout
#pragma unroll
  for (int nf = 0; nf < 2; ++nf) {
    const int lp = row0 + 16 * (nf * 2 + (kq >> 1));
    const int jo = 4 * (kq & 1);
    const int n0q = wn * 32 + nf * 16 + kq * 4;
#pragma unroll
    for (int ef = 0; ef < 8; ++ef) {
      const int ev = (e0 + ef * 16) < NE;
      const int e  = e0 + ef * 16 + row0;
      u16x4 zp4, hp4;
      zp4[0]=0; zp4[1]=0; zp4[2]=0; zp4[3]=0;
      hp4[0]=0; hp4[1]=0; hp4[2]=0; hp4[3]=0;
      if (ev) {
        zp4 = *(const u16x4*)(pre + (size_t)e * 768 + 256 + n0q);
        hp4 = *(const u16x4*)(pre + (size_t)e * 768 + 512 + n0q);
      }
      u16x4 hq;
#pragma unroll
      for (int v = 0; v < 4; ++v) {
        const float z  = sigm(b2f(zp4[v]) + aZ[nf][ef][v]);
        const float ph = tanh_f(b2f(hp4[v]) + aH[nf][ef][v]);
        float hn = (1.0f - z) * b2f(shq[nf][ef][v]) + z * ph;
        if (e == 0) hn = 0.f;                 // e_mask
        hq[v] = f2b(hn);
      }
      if (ev) *(u16x4*)(HB + (size_t)e * 512 + n0q) = hq;
      *(u16x4*)(sHn + (size_t)ef * 4096 + (size_t)(wn * 64 + lp) * 8 + jo) = hq;
    }
  }
  __syncthreads();

  // hu^T = Urp-frag x hnew-frag
  f32x4 aU[2][8];
#pragma unroll
  for (int nf = 0; nf < 2; ++nf)
#pragma unroll
    for (int ef = 0; ef < 8; ++ef) { aU[nf][ef][0]=0.f; aU[nf][ef][1]=0.f; aU[nf][ef][2]=0.f; aU[nf][ef][3]=0.f; }
#pragma unroll
  for (int kc = 0; kc < 8; ++kc) {
    short8 u0 = *(const short8*)(Urp + ((size_t)(kc * 16 + wn * 2 + 0) * 64 + lane) * 8);
    short8 u1 = *(const short8*)(Urp + ((size_t)(kc * 16 + wn * 2 + 1) * 64 + lane) * 8);
#pragma unroll
    for (int ef = 0; ef < 8; ++ef) {
      short8 hb = *(const short8*)(sHn + (size_t)ef * 4096 + (size_t)(kc * 64 + lane) * 8);
      aU[0][ef] = mfma16(u0, hb, aU[0][ef]);
      aU[1][ef] = mfma16(u1, hb, aU[1][ef]);
    }
  }
#pragma unroll
  for (int nf = 0; nf < 2; ++nf) {
    const int n0q = wn * 32 + nf * 16 + kq * 4;
#pragma unroll
    for (int ef = 0; ef < 8; ++ef) {
      const int ev = (e0 + ef * 16) < NE;
      const int e  = e0 + ef * 16 + row0;
      if (ev) {
        u16x4 uq;
#pragma unroll
        for (int v = 0; v < 4; ++v) uq[v] = f2b(aU[nf][ef][v]);
        *(u16x4*)(HB + (size_t)e * 512 + 256 + n0q) = uq;
      }
    }
  }
}

// ---------------- depth-0: hn = sigm(zpre)*tanh(hpre); hu = hn @ Ur ----------------
__global__ __launch_bounds__(256)
void step0(u16* __restrict__ HB, const u16* __restrict__ pre, const u16* __restrict__ Urp) {
  __shared__ __align__(16) u16 sH[32][264];
  const int tid = threadIdx.x, wave = tid >> 6, lane = tid & 63;
  const int e0 = blockIdx.x * 32;
  const int row0 = lane & 15, kq = lane >> 4;
#pragma unroll
  for (int mi = 0; mi < 2; ++mi)
#pragma unroll
    for (int ni = 0; ni < 4; ++ni)
#pragma unroll
      for (int v = 0; v < 4; ++v) {
        const int m = mi * 16 + kq * 4 + v;
        const int col = wave * 64 + ni * 16 + row0;
        const int e = e0 + m;
        const float zp = b2f(pre[(size_t)e * 768 + 256 + col]);
        const float hp = b2f(pre[(size_t)e * 768 + 512 + col]);
        float hn = sigm(zp) * tanh_f(hp);
        if (e == 0) hn = 0.f;
        const u16 hb = f2b(hn);
        HB[(size_t)e * 512 + col] = hb;
        sH[m][col] = hb;
      }
  __syncthreads();
  f32x4 accU[2][4];
#pragma unroll
  for (int i = 0; i < 2; ++i)
#pragma unroll
    for (int n = 0; n < 4; ++n) { accU[i][n][0]=0.f; accU[i][n][1]=0.f; accU[i][n][2]=0.f; accU[i][n][3]=0.f; }
#pragma unroll
  for (int s = 0; s < 8; ++s) {
    short8 a0 = *(const short8*)&sH[row0][s * 32 + kq * 8];
    short8 a1 = *(const short8*)&sH[row0 + 16][s * 32 + kq * 8];
#pragma unroll
    for (int ni = 0; ni < 4; ++ni) {
      short8 b = *(const short8*)(Urp + ((size_t)(s * 16 + wave * 4 + ni) * 64 + lane) * 8);
      accU[0][ni] = mfma16(a0, b, accU[0][ni]);
      accU[1][ni] = mfma16(a1, b, accU[1][ni]);
    }
  }
#pragma unroll
  for (int mi = 0; mi < 2; ++mi)
#pragma unroll
    for (int ni = 0; ni < 4; ++ni)
#pragma unroll
      for (int v = 0; v < 4; ++v) {
        const int m = mi * 16 + kq * 4 + v;
        const int col = wave * 64 + ni * 16 + row0;
        const int e = e0 + m;
        HB[(size_t)e * 512 + 256 + col] = f2b(accU[mi][ni][v]);
      }
}

// ---------------- readout ----------------
__global__ __launch_bounds__(256)
void readout(const u16* __restrict__ HB, const u16* __restrict__ fnp,
             const int* __restrict__ agraph, const u16* __restrict__ Wop,
             const float* __restrict__ bo, float* __restrict__ out) {
  __shared__ __align__(16) u16 sN[32][264];
  const int tid = threadIdx.x, wave = tid >> 6, lane = tid & 63;
  const int n0 = blockIdx.x * 32;
  const int row0 = lane & 15, kq = lane >> 4;

#pragma unroll 2
  for (int rr = 0; rr < 8; ++rr) {
    const int r = wave * 8 + rr;
    const int n = n0 + r;
    float s4[4] = {0.f, 0.f, 0.f, 0.f};
    if (n < NN) {
#pragma unroll
      for (int k = 0; k < 6; ++k) {
        const int idx = agraph[n * 6 + k];
        const u16x4 hv = *(const u16x4*)(HB + (size_t)idx * 512 + 4 * lane);
#pragma unroll
        for (int j = 0; j < 4; ++j) s4[j] += b2f(hv[j]);
      }
    }
#pragma unroll
    for (int j = 0; j < 4; ++j) sN[r][4 * lane + j] = f2b(s4[j]);
  }
  __syncthreads();

  f32x4 acc[2][4];
#pragma unroll
  for (int i = 0; i < 2; ++i)
#pragma unroll
    for (int n = 0; n < 4; ++n) { acc[i][n][0]=0.f; acc[i][n][1]=0.f; acc[i][n][2]=0.f; acc[i][n][3]=0.f; }
  const int ra = min(n0 + row0, NN - 1);
  const int rb = min(n0 + 16 + row0, NN - 1);
#pragma unroll
  for (int s = 0; s < 12; ++s) {
    short8 a0, a1;
    if (s < 4) {
      a0 = *(const short8*)(fnp + (size_t)ra * 128 + s * 32 + kq * 8);
      a1 = *(const short8*)(fnp + (size_t)rb * 128 + s * 32 + kq * 8);
    } else {
      a0 = *(const short8*)&sN[row0][(s - 4) * 32 + kq * 8];
      a1 = *(const short8*)&sN[row0 + 16][(s - 4) * 32 + kq * 8];
    }
#pragma unroll
    for (int ni = 0; ni < 4; ++ni) {
      short8 b = *(const short8*)(Wop + ((size_t)(s * 16 + wave * 4 + ni) * 64 + lane) * 8);
      acc[0][ni] = mfma16(a0, b, acc[0][ni]);
      acc[1][ni] = mfma16(a1, b, acc[1][ni]);
    }
  }
#pragma unroll
  for (int mi = 0; mi < 2; ++mi)
#pragma unroll
    for (int ni = 0; ni < 4; ++ni)
#pragma unroll
      for (int v = 0; v < 4; ++v) {
        const int m = mi * 16 + kq * 4 + v;
        const int col = wave * 64 + ni * 16 + row0;
        const int n = n0 + m;
        if (n < NN) {
          float val = fmaxf(acc[mi][ni][v] + bo[col], 0.f);
          if (n == 0) val = 0.f;             // n_mask
          out[(size_t)n * 256 + col] = val;
        }
      }
}

extern "C" void kernel_launch(void* const* d_in, const int* in_sizes, int n_in,
                              void* d_out, int out_size, void* d_ws, size_t ws_size,
                              hipStream_t stream) {
  const float* fnode      = (const float*)d_in[0];
  const int*   fmess_idx  = (const int*)d_in[1];
  const float* fmess_feat = (const float*)d_in[2];
  const int*   agraph     = (const int*)d_in[3];
  const int*   bgraph     = (const int*)d_in[4];
  const float* Wz         = (const float*)d_in[5];
  const float* bz         = (const float*)d_in[6];
  const float* Wr         = (const float*)d_in[7];
  const float* Ur         = (const float*)d_in[8];
  const float* bur        = (const float*)d_in[9];
  const float* Wh         = (const float*)d_in[10];
  const float* bh         = (const float*)d_in[11];
  const float* Wo         = (const float*)d_in[12];
  const float* bo         = (const float*)d_in[13];
  float* out = (float*)d_out;

  char* ws = (char*)d_ws;
  size_t off = 0;
  auto carve = [&](size_t bytes) -> char* {
    char* p = ws + off;
    off += (bytes + 511) & ~(size_t)511;
    return p;
  };
  u16* HB0   = (u16*)carve((size_t)NEP * 512 * 2);
  u16* HB1   = (u16*)carve((size_t)NEP * 512 * 2);
  u16* pre   = (u16*)carve((size_t)NE * 768 * 2);
  u16* hmess = (u16*)carve((size_t)NE * 128 * 2);
  u16* fnp   = (u16*)carve((size_t)NN * 128 * 2);
  u16* wpre  = (u16*)carve((size_t)3 * 98304 * 2);
  u16* wgate = (u16*)carve((size_t)3 * 131072 * 2);
  u16* urp   = (u16*)carve((size_t)3 * 65536 * 2);
  u16* wop   = (u16*)carve((size_t)3 * 98304 * 2);
  if (off > ws_size) return;

  pack_wpre <<<dim3(384, 3), 256, 0, stream>>>(Wr, Wz, Wh, wpre);
  pack_wgate<<<dim3(512, 3), 256, 0, stream>>>(Wz, Wh, wgate);
  pack_ur   <<<dim3(256, 3), 256, 0, stream>>>(Ur, urp);
  pack_wo   <<<dim3(384, 3), 256, 0, stream>>>(Wo, wop);
  embed_hmess<<<NE / 2, 256, 0, stream>>>(fnode, fmess_idx, fmess_feat, hmess);
  embed_fnode<<<NN / 2, 256, 0, stream>>>(fnode, fnp);

  for (int g = 0; g < 3; ++g) {
    pre_gemm<<<dim3(NE / 32, 3), 256, 0, stream>>>(
        hmess, wpre + (size_t)g * 98304, bur + g * 256, bz + g * 256, bh + g * 256, pre);
    const u16* wgate_g = wgate + (size_t)g * 131072;
    const u16* urp_g   = urp + (size_t)g * 65536;
    step0<<<NE / 32, 256, 0, stream>>>(HB0, pre, urp_g);
    u16* bufs[2] = {HB0, HB1};
    int cur = 0;
    for (int d = 1; d < 6; ++d) {
      gather_sums<<<NE / 8, 256, 0, stream>>>(bufs[cur], bufs[1 - cur], pre, bgraph);
      gru_step<<<NEP / 128, 512, 0, stream>>>(bufs[1 - cur], pre, wgate_g, urp_g);
      cur ^= 1;
    }
    readout<<<(NN + 31) / 32, 256, 0, stream>>>(
        bufs[cur], fnp, agraph, wop + (size_t)g * 98304, bo + g * 256, out + (size_t)g * NN * 256);
  }
}

// Round 6
// 5474.199 us; speedup vs baseline: 1.1776x; 1.1309x over previous
//
#include <hip/hip_runtime.h>

// D-MPNN (chemprop) x3 encoders on MI355X.
// Algebra: h_nei@Ur == (h@Ur)[bgraph]; hmess@W hoisted (zpre/hpre/r1b).
// R4: gru_step with 64-row blocks + deferred writes -> <=128 unified regs/wave
//     -> 2 blocks/CU (was 1, reg-capped). LDS 64->32KB.
// R5: resubmit unchanged after infra flake.

#define NE 100000   // messages
#define NEP 100032  // padded to 64-row blocks
#define NN 50000    // nodes

typedef unsigned short u16;
typedef short short8 __attribute__((ext_vector_type(8)));
typedef float f32x4 __attribute__((ext_vector_type(4)));
typedef unsigned short u16x4 __attribute__((ext_vector_type(4)));

__device__ __forceinline__ float b2f(u16 u) {
  union { unsigned int i; float f; } v; v.i = ((unsigned int)u) << 16; return v.f;
}
__device__ __forceinline__ u16 f2b(float f) {
  union { float f; unsigned int i; } v; v.f = f;
  unsigned int b = v.i;
  b += 0x7FFFu + ((b >> 16) & 1u);   // RTNE
  return (u16)(b >> 16);
}
__device__ __forceinline__ float sigm(float x) { return 1.0f / (1.0f + __expf(-x)); }
__device__ __forceinline__ float tanh_f(float x) { return 2.0f / (1.0f + __expf(-2.0f * x)) - 1.0f; }
__device__ __forceinline__ f32x4 mfma16(short8 a, short8 b, f32x4 c) {
  return __builtin_amdgcn_mfma_f32_16x16x32_bf16(a, b, c, 0, 0, 0);
}

// ---------------- weight packing (fragment-major) ----------------
// elem j of lane l at ((s*NB16+nb)*64+l)*8+j holds W[32*s+8*(l>>4)+j][16*nb+(l&15)]
// Works as either MFMA operand (A/B frag layouts are index-identical on gfx950).

__global__ void pack_wpre(const float* __restrict__ Wr, const float* __restrict__ Wz,
                          const float* __restrict__ Wh, u16* __restrict__ dst) {
  const int g = blockIdx.y;
  const int p = blockIdx.x * 256 + threadIdx.x;           // < 98304  (K=128,N=768)
  const int j = p & 7, l = (p >> 3) & 63, q = p >> 9;
  const int nb = q % 48, s = q / 48;
  const int k = 32 * s + 8 * (l >> 4) + j;
  const int n = 16 * nb + (l & 15);
  float v = 0.f;
  if (k < 104) {
    if (n < 256)      v = Wr[((size_t)g * 104 + k) * 256 + n];
    else if (n < 512) v = Wz[((size_t)g * 360 + k) * 256 + (n - 256)];
    else              v = Wh[((size_t)g * 360 + k) * 256 + (n - 512)];
  }
  dst[(size_t)g * 98304 + p] = f2b(v);
}

__global__ void pack_wgate(const float* __restrict__ Wz, const float* __restrict__ Wh,
                           u16* __restrict__ dst) {
  const int g = blockIdx.y;
  const int p = blockIdx.x * 256 + threadIdx.x;           // < 131072 (K=256,N=512)
  const int j = p & 7, l = (p >> 3) & 63, q = p >> 9;
  const int nb = q % 32, s = q / 32;
  const int k = 32 * s + 8 * (l >> 4) + j;
  const int n = 16 * nb + (l & 15);
  float v = (n < 256) ? Wz[((size_t)g * 360 + 104 + k) * 256 + n]
                      : Wh[((size_t)g * 360 + 104 + k) * 256 + (n - 256)];
  dst[(size_t)g * 131072 + p] = f2b(v);
}

__global__ void pack_ur(const float* __restrict__ Ur, u16* __restrict__ dst) {
  const int g = blockIdx.y;
  const int p = blockIdx.x * 256 + threadIdx.x;           // < 65536 (K=256,N=256)
  const int j = p & 7, l = (p >> 3) & 63, q = p >> 9;
  const int nb = q % 16, s = q / 16;
  const int k = 32 * s + 8 * (l >> 4) + j;
  const int n = 16 * nb + (l & 15);
  dst[(size_t)g * 65536 + p] = f2b(Ur[((size_t)g * 256 + k) * 256 + n]);
}

__global__ void pack_wo(const float* __restrict__ Wo, u16* __restrict__ dst) {
  const int g = blockIdx.y;
  const int p = blockIdx.x * 256 + threadIdx.x;           // < 98304 (K=384,N=256)
  const int j = p & 7, l = (p >> 3) & 63, q = p >> 9;
  const int nb = q % 16, s = q / 16;
  const int k = 32 * s + 8 * (l >> 4) + j;
  const int n = 16 * nb + (l & 15);
  float v = 0.f;
  if (k < 98)        v = Wo[((size_t)g * 354 + k) * 256 + n];        // fnode part
  else if (k >= 128) v = Wo[((size_t)g * 354 + (k - 30)) * 256 + n]; // nei part
  dst[(size_t)g * 98304 + p] = f2b(v);
}

// ---------------- embeddings ----------------
__global__ void embed_hmess(const float* __restrict__ fnode, const int* __restrict__ fmess_idx,
                            const float* __restrict__ fmess_feat, u16* __restrict__ hmess) {
  const int e = blockIdx.x * 2 + (threadIdx.x >> 7);
  const int c = threadIdx.x & 127;
  const int src = fmess_idx[e * 2];
  float v = 0.f;
  if (c < 98)       v = fnode[(size_t)src * 98 + c];
  else if (c < 104) v = fmess_feat[(size_t)e * 6 + (c - 98)];
  hmess[(size_t)e * 128 + c] = f2b(v);
}

__global__ void embed_fnode(const float* __restrict__ fnode, u16* __restrict__ fnp) {
  const int n = blockIdx.x * 2 + (threadIdx.x >> 7);
  const int c = threadIdx.x & 127;
  float v = (c < 98) ? fnode[(size_t)n * 98 + c] : 0.f;
  fnp[(size_t)n * 128 + c] = f2b(v);
}

// ---------------- pre-GEMM: pre[E][768] = hmess[E][128] @ Wpre + bias ----------------
__global__ __launch_bounds__(256)
void pre_gemm(const u16* __restrict__ hmess, const u16* __restrict__ Wpre,
              const float* __restrict__ bur, const float* __restrict__ bz,
              const float* __restrict__ bh, u16* __restrict__ pre) {
  const int tid = threadIdx.x, wave = tid >> 6, lane = tid & 63;
  const int e0 = blockIdx.x * 32;
  const int cchunk = blockIdx.y;
  const int row0 = lane & 15, kq = lane >> 4;
  f32x4 acc[2][4];
#pragma unroll
  for (int i = 0; i < 2; ++i)
#pragma unroll
    for (int n = 0; n < 4; ++n) { acc[i][n][0]=0.f; acc[i][n][1]=0.f; acc[i][n][2]=0.f; acc[i][n][3]=0.f; }
#pragma unroll
  for (int s = 0; s < 4; ++s) {
    short8 a0 = *(const short8*)(hmess + (size_t)(e0 + row0) * 128 + s * 32 + kq * 8);
    short8 a1 = *(const short8*)(hmess + (size_t)(e0 + 16 + row0) * 128 + s * 32 + kq * 8);
#pragma unroll
    for (int ni = 0; ni < 4; ++ni) {
      const int nb = cchunk * 16 + wave * 4 + ni;
      short8 b = *(const short8*)(Wpre + ((size_t)(s * 48 + nb) * 64 + lane) * 8);
      acc[0][ni] = mfma16(a0, b, acc[0][ni]);
      acc[1][ni] = mfma16(a1, b, acc[1][ni]);
    }
  }
  const float* bias = (cchunk == 0) ? bur : (cchunk == 1 ? bz : bh);
#pragma unroll
  for (int mi = 0; mi < 2; ++mi)
#pragma unroll
    for (int ni = 0; ni < 4; ++ni)
#pragma unroll
      for (int v = 0; v < 4; ++v) {
        const int m = mi * 16 + kq * 4 + v;
        const int col = cchunk * 256 + wave * 64 + ni * 16 + row0;
        const int e = e0 + m;
        pre[(size_t)e * 768 + col] = f2b(acc[mi][ni][v] + bias[col & 255]);
      }
}

// ---------------- gather: writes (sum_h|sum_gh) in MFMA B-frag layout ----------------
// frag addr for value (E, C): (E>>4)*8192 + ((C>>5)*64 + (E&15) + 16*((C>>3)&3))*8 + (C&7)
// (sh at s-chunks 0..7, sg at 8..15)
__global__ __launch_bounds__(256)
void gather_sums(const u16* __restrict__ HBin, u16* __restrict__ SG,
                 const u16* __restrict__ pre, const int* __restrict__ bgraph) {
  const int lane = threadIdx.x & 63;
  const int wid = (int)((blockIdx.x * 256 + threadIdx.x) >> 6);   // wave-uniform

  int idx[2][6];
#pragma unroll
  for (int m = 0; m < 2; ++m)
#pragma unroll
    for (int k = 0; k < 6; ++k)
      idx[m][k] = bgraph[(wid * 2 + m) * 6 + k];

  float r1f[2][4];
#pragma unroll
  for (int m = 0; m < 2; ++m) {
    const u16x4 r1v = *(const u16x4*)(pre + (size_t)(wid * 2 + m) * 768 + 4 * lane);
#pragma unroll
    for (int j = 0; j < 4; ++j) r1f[m][j] = b2f(r1v[j]);
  }

  u16x4 hv[2][6], huv[2][6];
#pragma unroll
  for (int m = 0; m < 2; ++m)
#pragma unroll
    for (int k = 0; k < 6; ++k) {
      const u16* row = HBin + (size_t)idx[m][k] * 512;
      hv[m][k]  = *(const u16x4*)(row + 4 * lane);
      huv[m][k] = *(const u16x4*)(row + 256 + 4 * lane);
    }

#pragma unroll
  for (int m = 0; m < 2; ++m) {
    const int e = wid * 2 + m;
    float sh[4] = {0.f, 0.f, 0.f, 0.f}, sg[4] = {0.f, 0.f, 0.f, 0.f};
#pragma unroll
    for (int k = 0; k < 6; ++k)
#pragma unroll
      for (int j = 0; j < 4; ++j) {
        const float h  = b2f(hv[m][k][j]);
        const float rg = sigm(r1f[m][j] + b2f(huv[m][k][j]));
        sh[j] += h;
        sg[j] += rg * h;
      }
    u16x4 o0, o1;
#pragma unroll
    for (int j = 0; j < 4; ++j) { o0[j] = f2b(sh[j]); o1[j] = f2b(sg[j]); }
    // lane holds cols C = 4*lane .. 4*lane+3
    const size_t gb = (size_t)(e >> 4) * 8192;
    const int lsh = (((lane >> 3) * 64) + (e & 15) + 16 * ((lane >> 1) & 3)) * 8 + 4 * (lane & 1);
    *(u16x4*)(SG + gb + lsh) = o0;          // sh: s = lane>>3
    *(u16x4*)(SG + gb + lsh + 4096) = o1;   // sg: s + 8
  }
}

// ---------------- GRU step (transposed): HB holds frag (sh|sg) on entry, natural (h|hu) on exit
// 64 e-rows/block, 8 waves: wave wn owns output n in [wn*32, wn*32+32).
// Deferred-write structure keeps peak at ~120 unified regs -> 2 blocks/CU.
__global__ __launch_bounds__(512, 4)
void gru_step(u16* __restrict__ HB, const u16* __restrict__ pre,
              const u16* __restrict__ Wgate, const u16* __restrict__ Urp) {
  __shared__ __align__(16) u16 sHn[16384];   // 32KB: hnew frag (4 ef x 16 rows x 256 k)
  const int tid = threadIdx.x;
  const int wn = tid >> 6, lane = tid & 63;
  const int row0 = lane & 15, kq = lane >> 4;
  const int e0 = blockIdx.x * 64;
  u16* SGb = HB + (size_t)(e0 >> 4) * 8192;

  f32x4 aZ[2][4], aH[2][4];
#pragma unroll
  for (int nf = 0; nf < 2; ++nf)
#pragma unroll
    for (int ef = 0; ef < 4; ++ef) {
      aZ[nf][ef][0]=0.f; aZ[nf][ef][1]=0.f; aZ[nf][ef][2]=0.f; aZ[nf][ef][3]=0.f;
      aH[nf][ef][0]=0.f; aH[nf][ef][1]=0.f; aH[nf][ef][2]=0.f; aH[nf][ef][3]=0.f;
    }

  // gate GEMMs: gz^T = Wz2-frag x sh-frag, gh^T = Wh2-frag x sg-frag
#pragma unroll
  for (int kc = 0; kc < 8; ++kc) {
    short8 wz0 = *(const short8*)(Wgate + ((size_t)(kc * 32 + wn * 2 + 0) * 64 + lane) * 8);
    short8 wz1 = *(const short8*)(Wgate + ((size_t)(kc * 32 + wn * 2 + 1) * 64 + lane) * 8);
    short8 wh0 = *(const short8*)(Wgate + ((size_t)(kc * 32 + 16 + wn * 2 + 0) * 64 + lane) * 8);
    short8 wh1 = *(const short8*)(Wgate + ((size_t)(kc * 32 + 16 + wn * 2 + 1) * 64 + lane) * 8);
#pragma unroll
    for (int ef = 0; ef < 4; ++ef) {
      short8 bsh = *(const short8*)(SGb + (size_t)ef * 8192 + (size_t)(kc * 64 + lane) * 8);
      short8 bsg = *(const short8*)(SGb + (size_t)ef * 8192 + (size_t)((8 + kc) * 64 + lane) * 8);
      aZ[0][ef] = mfma16(wz0, bsh, aZ[0][ef]);
      aZ[1][ef] = mfma16(wz1, bsh, aZ[1][ef]);
      aH[0][ef] = mfma16(wh0, bsg, aH[0][ef]);
      aH[1][ef] = mfma16(wh1, bsg, aH[1][ef]);
    }
  }

  // GRU epilogue into registers only (HB still readable by other waves)
  u16x4 hn[2][4];
#pragma unroll
  for (int nf = 0; nf < 2; ++nf) {
    const int n0q = wn * 32 + nf * 16 + kq * 4;
    const int lp = row0 + 16 * (nf * 2 + (kq >> 1));
    const int jo = 4 * (kq & 1);
#pragma unroll
    for (int ef = 0; ef < 4; ++ef) {
      const int ev = (e0 + ef * 16) < NE;
      const int e  = e0 + ef * 16 + row0;
      const u16x4 shv = *(const u16x4*)(SGb + (size_t)ef * 8192 + (size_t)(wn * 64 + lp) * 8 + jo);
      u16x4 zp4, hp4;
      zp4[0]=0; zp4[1]=0; zp4[2]=0; zp4[3]=0;
      hp4[0]=0; hp4[1]=0; hp4[2]=0; hp4[3]=0;
      if (ev) {
        zp4 = *(const u16x4*)(pre + (size_t)e * 768 + 256 + n0q);
        hp4 = *(const u16x4*)(pre + (size_t)e * 768 + 512 + n0q);
      }
#pragma unroll
      for (int v = 0; v < 4; ++v) {
        const float z  = sigm(b2f(zp4[v]) + aZ[nf][ef][v]);
        const float ph = tanh_f(b2f(hp4[v]) + aH[nf][ef][v]);
        float hf = (1.0f - z) * b2f(shv[v]) + z * ph;
        if (e == 0) hf = 0.f;                 // e_mask
        hn[nf][ef][v] = f2b(hf);
      }
    }
  }
  __syncthreads();   // B1: all frag reads complete block-wide -> safe to overwrite

  // natural h write + sHn frag write
#pragma unroll
  for (int nf = 0; nf < 2; ++nf) {
    const int n0q = wn * 32 + nf * 16 + kq * 4;
    const int lp = row0 + 16 * (nf * 2 + (kq >> 1));
    const int jo = 4 * (kq & 1);
#pragma unroll
    for (int ef = 0; ef < 4; ++ef) {
      const int ev = (e0 + ef * 16) < NE;
      const int e  = e0 + ef * 16 + row0;
      if (ev) *(u16x4*)(HB + (size_t)e * 512 + n0q) = hn[nf][ef];
      *(u16x4*)(sHn + (size_t)ef * 4096 + (size_t)(wn * 64 + lp) * 8 + jo) = hn[nf][ef];
    }
  }
  __syncthreads();   // B2: sHn ready

  // hu^T = Urp-frag x hnew-frag
  f32x4 aU[2][4];
#pragma unroll
  for (int nf = 0; nf < 2; ++nf)
#pragma unroll
    for (int ef = 0; ef < 4; ++ef) { aU[nf][ef][0]=0.f; aU[nf][ef][1]=0.f; aU[nf][ef][2]=0.f; aU[nf][ef][3]=0.f; }
#pragma unroll
  for (int kc = 0; kc < 8; ++kc) {
    short8 u0 = *(const short8*)(Urp + ((size_t)(kc * 16 + wn * 2 + 0) * 64 + lane) * 8);
    short8 u1 = *(const short8*)(Urp + ((size_t)(kc * 16 + wn * 2 + 1) * 64 + lane) * 8);
#pragma unroll
    for (int ef = 0; ef < 4; ++ef) {
      short8 hb = *(const short8*)(sHn + (size_t)ef * 4096 + (size_t)(kc * 64 + lane) * 8);
      aU[0][ef] = mfma16(u0, hb, aU[0][ef]);
      aU[1][ef] = mfma16(u1, hb, aU[1][ef]);
    }
  }
#pragma unroll
  for (int nf = 0; nf < 2; ++nf) {
    const int n0q = wn * 32 + nf * 16 + kq * 4;
#pragma unroll
    for (int ef = 0; ef < 4; ++ef) {
      const int ev = (e0 + ef * 16) < NE;
      const int e  = e0 + ef * 16 + row0;
      if (ev) {
        u16x4 uq;
#pragma unroll
        for (int v = 0; v < 4; ++v) uq[v] = f2b(aU[nf][ef][v]);
        *(u16x4*)(HB + (size_t)e * 512 + 256 + n0q) = uq;
      }
    }
  }
}

// ---------------- depth-0: hn = sigm(zpre)*tanh(hpre); hu = hn @ Ur ----------------
__global__ __launch_bounds__(256)
void step0(u16* __restrict__ HB, const u16* __restrict__ pre, const u16* __restrict__ Urp) {
  __shared__ __align__(16) u16 sH[32][264];
  const int tid = threadIdx.x, wave = tid >> 6, lane = tid & 63;
  const int e0 = blockIdx.x * 32;
  const int row0 = lane & 15, kq = lane >> 4;
#pragma unroll
  for (int mi = 0; mi < 2; ++mi)
#pragma unroll
    for (int ni = 0; ni < 4; ++ni)
#pragma unroll
      for (int v = 0; v < 4; ++v) {
        const int m = mi * 16 + kq * 4 + v;
        const int col = wave * 64 + ni * 16 + row0;
        const int e = e0 + m;
        const float zp = b2f(pre[(size_t)e * 768 + 256 + col]);
        const float hp = b2f(pre[(size_t)e * 768 + 512 + col]);
        float hn = sigm(zp) * tanh_f(hp);
        if (e == 0) hn = 0.f;
        const u16 hb = f2b(hn);
        HB[(size_t)e * 512 + col] = hb;
        sH[m][col] = hb;
      }
  __syncthreads();
  f32x4 accU[2][4];
#pragma unroll
  for (int i = 0; i < 2; ++i)
#pragma unroll
    for (int n = 0; n < 4; ++n) { accU[i][n][0]=0.f; accU[i][n][1]=0.f; accU[i][n][2]=0.f; accU[i][n][3]=0.f; }
#pragma unroll
  for (int s = 0; s < 8; ++s) {
    short8 a0 = *(const short8*)&sH[row0][s * 32 + kq * 8];
    short8 a1 = *(const short8*)&sH[row0 + 16][s * 32 + kq * 8];
#pragma unroll
    for (int ni = 0; ni < 4; ++ni) {
      short8 b = *(const short8*)(Urp + ((size_t)(s * 16 + wave * 4 + ni) * 64 + lane) * 8);
      accU[0][ni] = mfma16(a0, b, accU[0][ni]);
      accU[1][ni] = mfma16(a1, b, accU[1][ni]);
    }
  }
#pragma unroll
  for (int mi = 0; mi < 2; ++mi)
#pragma unroll
    for (int ni = 0; ni < 4; ++ni)
#pragma unroll
      for (int v = 0; v < 4; ++v) {
        const int m = mi * 16 + kq * 4 + v;
        const int col = wave * 64 + ni * 16 + row0;
        const int e = e0 + m;
        HB[(size_t)e * 512 + 256 + col] = f2b(accU[mi][ni][v]);
      }
}

// ---------------- readout ----------------
__global__ __launch_bounds__(256)
void readout(const u16* __restrict__ HB, const u16* __restrict__ fnp,
             const int* __restrict__ agraph, const u16* __restrict__ Wop,
             const float* __restrict__ bo, float* __restrict__ out) {
  __shared__ __align__(16) u16 sN[32][264];
  const int tid = threadIdx.x, wave = tid >> 6, lane = tid & 63;
  const int n0 = blockIdx.x * 32;
  const int row0 = lane & 15, kq = lane >> 4;

#pragma unroll 2
  for (int rr = 0; rr < 8; ++rr) {
    const int r = wave * 8 + rr;
    const int n = n0 + r;
    float s4[4] = {0.f, 0.f, 0.f, 0.f};
    if (n < NN) {
#pragma unroll
      for (int k = 0; k < 6; ++k) {
        const int idx = agraph[n * 6 + k];
        const u16x4 hv = *(const u16x4*)(HB + (size_t)idx * 512 + 4 * lane);
#pragma unroll
        for (int j = 0; j < 4; ++j) s4[j] += b2f(hv[j]);
      }
    }
#pragma unroll
    for (int j = 0; j < 4; ++j) sN[r][4 * lane + j] = f2b(s4[j]);
  }
  __syncthreads();

  f32x4 acc[2][4];
#pragma unroll
  for (int i = 0; i < 2; ++i)
#pragma unroll
    for (int n = 0; n < 4; ++n) { acc[i][n][0]=0.f; acc[i][n][1]=0.f; acc[i][n][2]=0.f; acc[i][n][3]=0.f; }
  const int ra = min(n0 + row0, NN - 1);
  const int rb = min(n0 + 16 + row0, NN - 1);
#pragma unroll
  for (int s = 0; s < 12; ++s) {
    short8 a0, a1;
    if (s < 4) {
      a0 = *(const short8*)(fnp + (size_t)ra * 128 + s * 32 + kq * 8);
      a1 = *(const short8*)(fnp + (size_t)rb * 128 + s * 32 + kq * 8);
    } else {
      a0 = *(const short8*)&sN[row0][(s - 4) * 32 + kq * 8];
      a1 = *(const short8*)&sN[row0 + 16][(s - 4) * 32 + kq * 8];
    }
#pragma unroll
    for (int ni = 0; ni < 4; ++ni) {
      short8 b = *(const short8*)(Wop + ((size_t)(s * 16 + wave * 4 + ni) * 64 + lane) * 8);
      acc[0][ni] = mfma16(a0, b, acc[0][ni]);
      acc[1][ni] = mfma16(a1, b, acc[1][ni]);
    }
  }
#pragma unroll
  for (int mi = 0; mi < 2; ++mi)
#pragma unroll
    for (int ni = 0; ni < 4; ++ni)
#pragma unroll
      for (int v = 0; v < 4; ++v) {
        const int m = mi * 16 + kq * 4 + v;
        const int col = wave * 64 + ni * 16 + row0;
        const int n = n0 + m;
        if (n < NN) {
          float val = fmaxf(acc[mi][ni][v] + bo[col], 0.f);
          if (n == 0) val = 0.f;             // n_mask
          out[(size_t)n * 256 + col] = val;
        }
      }
}

extern "C" void kernel_launch(void* const* d_in, const int* in_sizes, int n_in,
                              void* d_out, int out_size, void* d_ws, size_t ws_size,
                              hipStream_t stream) {
  const float* fnode      = (const float*)d_in[0];
  const int*   fmess_idx  = (const int*)d_in[1];
  const float* fmess_feat = (const float*)d_in[2];
  const int*   agraph     = (const int*)d_in[3];
  const int*   bgraph     = (const int*)d_in[4];
  const float* Wz         = (const float*)d_in[5];
  const float* bz         = (const float*)d_in[6];
  const float* Wr         = (const float*)d_in[7];
  const float* Ur         = (const float*)d_in[8];
  const float* bur        = (const float*)d_in[9];
  const float* Wh         = (const float*)d_in[10];
  const float* bh         = (const float*)d_in[11];
  const float* Wo         = (const float*)d_in[12];
  const float* bo         = (const float*)d_in[13];
  float* out = (float*)d_out;

  char* ws = (char*)d_ws;
  size_t off = 0;
  auto carve = [&](size_t bytes) -> char* {
    char* p = ws + off;
    off += (bytes + 511) & ~(size_t)511;
    return p;
  };
  u16* HB0   = (u16*)carve((size_t)NEP * 512 * 2);
  u16* HB1   = (u16*)carve((size_t)NEP * 512 * 2);
  u16* pre   = (u16*)carve((size_t)NE * 768 * 2);
  u16* hmess = (u16*)carve((size_t)NE * 128 * 2);
  u16* fnp   = (u16*)carve((size_t)NN * 128 * 2);
  u16* wpre  = (u16*)carve((size_t)3 * 98304 * 2);
  u16* wgate = (u16*)carve((size_t)3 * 131072 * 2);
  u16* urp   = (u16*)carve((size_t)3 * 65536 * 2);
  u16* wop   = (u16*)carve((size_t)3 * 98304 * 2);
  if (off > ws_size) return;

  pack_wpre <<<dim3(384, 3), 256, 0, stream>>>(Wr, Wz, Wh, wpre);
  pack_wgate<<<dim3(512, 3), 256, 0, stream>>>(Wz, Wh, wgate);
  pack_ur   <<<dim3(256, 3), 256, 0, stream>>>(Ur, urp);
  pack_wo   <<<dim3(384, 3), 256, 0, stream>>>(Wo, wop);
  embed_hmess<<<NE / 2, 256, 0, stream>>>(fnode, fmess_idx, fmess_feat, hmess);
  embed_fnode<<<NN / 2, 256, 0, stream>>>(fnode, fnp);

  for (int g = 0; g < 3; ++g) {
    pre_gemm<<<dim3(NE / 32, 3), 256, 0, stream>>>(
        hmess, wpre + (size_t)g * 98304, bur + g * 256, bz + g * 256, bh + g * 256, pre);
    const u16* wgate_g = wgate + (size_t)g * 131072;
    const u16* urp_g   = urp + (size_t)g * 65536;
    step0<<<NE / 32, 256, 0, stream>>>(HB0, pre, urp_g);
    u16* bufs[2] = {HB0, HB1};
    int cur = 0;
    for (int d = 1; d < 6; ++d) {
      gather_sums<<<NE / 8, 256, 0, stream>>>(bufs[cur], bufs[1 - cur], pre, bgraph);
      gru_step<<<NEP / 64, 512, 0, stream>>>(bufs[1 - cur], pre, wgate_g, urp_g);
      cur ^= 1;
    }
    readout<<<(NN + 31) / 32, 256, 0, stream>>>(
        bufs[cur], fnp, agraph, wop + (size_t)g * 98304, bo + g * 256, out + (size_t)g * NN * 256);
  }
}

// Round 7
// 4451.344 us; speedup vs baseline: 1.4482x; 1.2298x over previous
//
#include <hip/hip_runtime.h>

// D-MPNN (chemprop) x3 encoders on MI355X.
// Algebra: h_nei@Ur == (h@Ur)[bgraph]; hmess@W hoisted (r1b/zpre/hpre).
// R6: kill partial-line traffic. zpre/hpre in D-frag layout (pre_gemm_t,
//     transposed like gru_step); h/hu natural writes via LDS transpose;
//     gather assembles full 16-row frag blocks in LDS -> 16KB coalesced out.

#define NE 100000   // messages
#define NEP 100032  // padded to 64-row blocks
#define NN 50000    // nodes

typedef unsigned short u16;
typedef short short8 __attribute__((ext_vector_type(8)));
typedef float f32x4 __attribute__((ext_vector_type(4)));
typedef unsigned short u16x4 __attribute__((ext_vector_type(4)));

__device__ __forceinline__ float b2f(u16 u) {
  union { unsigned int i; float f; } v; v.i = ((unsigned int)u) << 16; return v.f;
}
__device__ __forceinline__ u16 f2b(float f) {
  union { float f; unsigned int i; } v; v.f = f;
  unsigned int b = v.i;
  b += 0x7FFFu + ((b >> 16) & 1u);   // RTNE
  return (u16)(b >> 16);
}
__device__ __forceinline__ float sigm(float x) { return 1.0f / (1.0f + __expf(-x)); }
__device__ __forceinline__ float tanh_f(float x) { return 2.0f / (1.0f + __expf(-2.0f * x)) - 1.0f; }
__device__ __forceinline__ f32x4 mfma16(short8 a, short8 b, f32x4 c) {
  return __builtin_amdgcn_mfma_f32_16x16x32_bf16(a, b, c, 0, 0, 0);
}

// ---------------- weight packing (fragment-major) ----------------
// elem j of lane l at ((s*NB16+nb)*64+l)*8+j holds W[32*s+8*(l>>4)+j][16*nb+(l&15)]

__global__ void pack_wpre(const float* __restrict__ Wr, const float* __restrict__ Wz,
                          const float* __restrict__ Wh, u16* __restrict__ dst) {
  const int g = blockIdx.y;
  const int p = blockIdx.x * 256 + threadIdx.x;           // < 98304  (K=128,N=768)
  const int j = p & 7, l = (p >> 3) & 63, q = p >> 9;
  const int nb = q % 48, s = q / 48;
  const int k = 32 * s + 8 * (l >> 4) + j;
  const int n = 16 * nb + (l & 15);
  float v = 0.f;
  if (k < 104) {
    if (n < 256)      v = Wr[((size_t)g * 104 + k) * 256 + n];
    else if (n < 512) v = Wz[((size_t)g * 360 + k) * 256 + (n - 256)];
    else              v = Wh[((size_t)g * 360 + k) * 256 + (n - 512)];
  }
  dst[(size_t)g * 98304 + p] = f2b(v);
}

__global__ void pack_wgate(const float* __restrict__ Wz, const float* __restrict__ Wh,
                           u16* __restrict__ dst) {
  const int g = blockIdx.y;
  const int p = blockIdx.x * 256 + threadIdx.x;           // < 131072 (K=256,N=512)
  const int j = p & 7, l = (p >> 3) & 63, q = p >> 9;
  const int nb = q % 32, s = q / 32;
  const int k = 32 * s + 8 * (l >> 4) + j;
  const int n = 16 * nb + (l & 15);
  float v = (n < 256) ? Wz[((size_t)g * 360 + 104 + k) * 256 + n]
                      : Wh[((size_t)g * 360 + 104 + k) * 256 + (n - 256)];
  dst[(size_t)g * 131072 + p] = f2b(v);
}

__global__ void pack_ur(const float* __restrict__ Ur, u16* __restrict__ dst) {
  const int g = blockIdx.y;
  const int p = blockIdx.x * 256 + threadIdx.x;           // < 65536 (K=256,N=256)
  const int j = p & 7, l = (p >> 3) & 63, q = p >> 9;
  const int nb = q % 16, s = q / 16;
  const int k = 32 * s + 8 * (l >> 4) + j;
  const int n = 16 * nb + (l & 15);
  dst[(size_t)g * 65536 + p] = f2b(Ur[((size_t)g * 256 + k) * 256 + n]);
}

__global__ void pack_wo(const float* __restrict__ Wo, u16* __restrict__ dst) {
  const int g = blockIdx.y;
  const int p = blockIdx.x * 256 + threadIdx.x;           // < 98304 (K=384,N=256)
  const int j = p & 7, l = (p >> 3) & 63, q = p >> 9;
  const int nb = q % 16, s = q / 16;
  const int k = 32 * s + 8 * (l >> 4) + j;
  const int n = 16 * nb + (l & 15);
  float v = 0.f;
  if (k < 98)        v = Wo[((size_t)g * 354 + k) * 256 + n];        // fnode part
  else if (k >= 128) v = Wo[((size_t)g * 354 + (k - 30)) * 256 + n]; // nei part
  dst[(size_t)g * 98304 + p] = f2b(v);
}

// ---------------- embeddings ----------------
// hmess in B-frag layout: (e,k) -> (e>>4)*2048 + ((k>>5)*64 + (e&15) + 16*((k>>3)&3))*8 + (k&7)
__global__ void embed_hmess_f(const float* __restrict__ fnode, const int* __restrict__ fmess_idx,
                              const float* __restrict__ fmess_feat, u16* __restrict__ hmF) {
  const int e = blockIdx.x * 2 + (threadIdx.x >> 7);
  const int c = threadIdx.x & 127;
  const int src = fmess_idx[e * 2];
  float v = 0.f;
  if (c < 98)       v = fnode[(size_t)src * 98 + c];
  else if (c < 104) v = fmess_feat[(size_t)e * 6 + (c - 98)];
  hmF[(size_t)(e >> 4) * 2048 + ((c >> 5) * 64 + (e & 15) + 16 * ((c >> 3) & 3)) * 8 + (c & 7)] = f2b(v);
}

__global__ void embed_fnode(const float* __restrict__ fnode, u16* __restrict__ fnp) {
  const int n = blockIdx.x * 2 + (threadIdx.x >> 7);
  const int c = threadIdx.x & 127;
  float v = (c < 98) ? fnode[(size_t)n * 98 + c] : 0.f;
  fnp[(size_t)n * 128 + c] = f2b(v);
}

// ---------------- pre-GEMM (transposed): r1b natural [e][256]; zpre/hpre in D-frag tiles ----
// D-frag tile (ec,nc): 256 u16, element (lane,v) = (e=ec*16+(lane&15), n=nc*16+(lane>>4)*4+v)
// at tilebase + lane*4 + v.
__global__ __launch_bounds__(256)
void pre_gemm_t(const u16* __restrict__ hmF, const u16* __restrict__ Wpre,
                const float* __restrict__ bur, const float* __restrict__ bz,
                const float* __restrict__ bh, u16* __restrict__ r1b,
                u16* __restrict__ zpF, u16* __restrict__ hpF) {
  const int tid = threadIdx.x, wave = tid >> 6, lane = tid & 63;
  const int row0 = lane & 15, kq = lane >> 4;
  const int e0 = blockIdx.x * 32;
  const int cchunk = blockIdx.y;
  f32x4 acc[2][4];   // [ef][nf]
#pragma unroll
  for (int i = 0; i < 2; ++i)
#pragma unroll
    for (int n = 0; n < 4; ++n) { acc[i][n][0]=0.f; acc[i][n][1]=0.f; acc[i][n][2]=0.f; acc[i][n][3]=0.f; }
#pragma unroll
  for (int kc = 0; kc < 4; ++kc) {
    short8 bf[2];
#pragma unroll
    for (int ef = 0; ef < 2; ++ef)
      bf[ef] = *(const short8*)(hmF + (size_t)((e0 >> 4) + ef) * 2048 + (size_t)(kc * 64 + lane) * 8);
#pragma unroll
    for (int nf = 0; nf < 4; ++nf) {
      const int nb = cchunk * 16 + wave * 4 + nf;
      short8 wf = *(const short8*)(Wpre + ((size_t)(kc * 48 + nb) * 64 + lane) * 8);
      acc[0][nf] = mfma16(wf, bf[0], acc[0][nf]);
      acc[1][nf] = mfma16(wf, bf[1], acc[1][nf]);
    }
  }
  const float* bias = (cchunk == 0) ? bur : (cchunk == 1 ? bz : bh);
  u16* dstF = (cchunk == 1) ? zpF : hpF;
#pragma unroll
  for (int ef = 0; ef < 2; ++ef)
#pragma unroll
    for (int nf = 0; nf < 4; ++nf) {
      const int n256 = wave * 64 + nf * 16 + kq * 4;
      const int e = e0 + ef * 16 + row0;
      u16x4 o;
#pragma unroll
      for (int v = 0; v < 4; ++v) o[v] = f2b(acc[ef][nf][v] + bias[n256 + v]);
      if (cchunk == 0) {
        *(u16x4*)(r1b + (size_t)e * 256 + n256) = o;
      } else {
        *(u16x4*)(dstF + ((size_t)((e0 >> 4) + ef) * 16 + (wave * 4 + nf)) * 256 + lane * 4) = o;
      }
    }
}

// ---------------- gather: assemble one 16-row SG frag block in LDS, coalesced 16KB out ----
__global__ __launch_bounds__(512)
void gather_sums(const u16* __restrict__ HBin, u16* __restrict__ SG,
                 const u16* __restrict__ r1b, const int* __restrict__ bgraph) {
  __shared__ __align__(16) u16 sF[8192];   // [sh 4096][sg 4096]
  const int tid = threadIdx.x, lane = tid & 63, w = tid >> 6;
  const int e_base = blockIdx.x * 16;

  int idx[2][6];
#pragma unroll
  for (int m = 0; m < 2; ++m)
#pragma unroll
    for (int k = 0; k < 6; ++k)
      idx[m][k] = bgraph[(e_base + w * 2 + m) * 6 + k];

  float r1f[2][4];
#pragma unroll
  for (int m = 0; m < 2; ++m) {
    const u16x4 r1v = *(const u16x4*)(r1b + (size_t)(e_base + w * 2 + m) * 256 + 4 * lane);
#pragma unroll
    for (int j = 0; j < 4; ++j) r1f[m][j] = b2f(r1v[j]);
  }

  u16x4 hv[2][6], huv[2][6];
#pragma unroll
  for (int m = 0; m < 2; ++m)
#pragma unroll
    for (int k = 0; k < 6; ++k) {
      const u16* row = HBin + (size_t)idx[m][k] * 512;
      hv[m][k]  = *(const u16x4*)(row + 4 * lane);
      huv[m][k] = *(const u16x4*)(row + 256 + 4 * lane);
    }

  const int c0 = 4 * lane;
  const int offc = ((c0 >> 5) * 64 + 16 * ((c0 >> 3) & 3)) * 8 + (c0 & 7);
#pragma unroll
  for (int m = 0; m < 2; ++m) {
    const int e = e_base + w * 2 + m;
    float sh[4] = {0.f, 0.f, 0.f, 0.f}, sg[4] = {0.f, 0.f, 0.f, 0.f};
#pragma unroll
    for (int k = 0; k < 6; ++k)
#pragma unroll
      for (int j = 0; j < 4; ++j) {
        const float h  = b2f(hv[m][k][j]);
        const float rg = sigm(r1f[m][j] + b2f(huv[m][k][j]));
        sh[j] += h;
        sg[j] += rg * h;
      }
    u16x4 o0, o1;
#pragma unroll
    for (int j = 0; j < 4; ++j) { o0[j] = f2b(sh[j]); o1[j] = f2b(sg[j]); }
    const int off = offc + (e & 15) * 8;
    *(u16x4*)(sF + off) = o0;
    *(u16x4*)(sF + 4096 + off) = o1;
  }
  __syncthreads();
  u16* dst = SG + (size_t)(e_base >> 4) * 8192;
  *(short8*)(dst + tid * 16)     = *(const short8*)(sF + tid * 16);
  *(short8*)(dst + tid * 16 + 8) = *(const short8*)(sF + tid * 16 + 8);
}

// ---------------- GRU step: SG frag in, natural (h|hu) out, all coalesced ----------------
__global__ __launch_bounds__(512, 4)
void gru_step(u16* __restrict__ HB, const u16* __restrict__ zpF, const u16* __restrict__ hpF,
              const u16* __restrict__ Wgate, const u16* __restrict__ Urp) {
  __shared__ __align__(16) u16 sHn[16384];   // 32KB frag staging (hnew, then hu)
  const int tid = threadIdx.x;
  const int wn = tid >> 6, lane = tid & 63;
  const int row0 = lane & 15, kq = lane >> 4;
  const int e0 = blockIdx.x * 64;
  u16* SGb = HB + (size_t)(e0 >> 4) * 8192;

  f32x4 aZ[2][4], aH[2][4];
#pragma unroll
  for (int nf = 0; nf < 2; ++nf)
#pragma unroll
    for (int ef = 0; ef < 4; ++ef) {
      aZ[nf][ef][0]=0.f; aZ[nf][ef][1]=0.f; aZ[nf][ef][2]=0.f; aZ[nf][ef][3]=0.f;
      aH[nf][ef][0]=0.f; aH[nf][ef][1]=0.f; aH[nf][ef][2]=0.f; aH[nf][ef][3]=0.f;
    }

  // gate GEMMs
#pragma unroll
  for (int kc = 0; kc < 8; ++kc) {
    short8 wz0 = *(const short8*)(Wgate + ((size_t)(kc * 32 + wn * 2 + 0) * 64 + lane) * 8);
    short8 wz1 = *(const short8*)(Wgate + ((size_t)(kc * 32 + wn * 2 + 1) * 64 + lane) * 8);
    short8 wh0 = *(const short8*)(Wgate + ((size_t)(kc * 32 + 16 + wn * 2 + 0) * 64 + lane) * 8);
    short8 wh1 = *(const short8*)(Wgate + ((size_t)(kc * 32 + 16 + wn * 2 + 1) * 64 + lane) * 8);
#pragma unroll
    for (int ef = 0; ef < 4; ++ef) {
      short8 bsh = *(const short8*)(SGb + (size_t)ef * 8192 + (size_t)(kc * 64 + lane) * 8);
      short8 bsg = *(const short8*)(SGb + (size_t)ef * 8192 + (size_t)((8 + kc) * 64 + lane) * 8);
      aZ[0][ef] = mfma16(wz0, bsh, aZ[0][ef]);
      aZ[1][ef] = mfma16(wz1, bsh, aZ[1][ef]);
      aH[0][ef] = mfma16(wh0, bsg, aH[0][ef]);
      aH[1][ef] = mfma16(wh1, bsg, aH[1][ef]);
    }
  }

  // GRU epilogue into registers; zp/hp reads are frag-coalesced
#pragma unroll
  for (int nf = 0; nf < 2; ++nf) {
    const int lp = row0 + 16 * (nf * 2 + (kq >> 1));
    const int jo = 4 * (kq & 1);
    const int nc = wn * 2 + nf;
#pragma unroll
    for (int ef = 0; ef < 4; ++ef) {
      const int ev = (e0 + ef * 16) < NE;
      const int e  = e0 + ef * 16 + row0;
      const u16x4 shv = *(const u16x4*)(SGb + (size_t)ef * 8192 + (size_t)(wn * 64 + lp) * 8 + jo);
      const size_t tb = ((size_t)((e0 >> 4) + ef) * 16 + nc) * 256 + lane * 4;
      const u16x4 zp4 = *(const u16x4*)(zpF + tb);
      const u16x4 hp4 = *(const u16x4*)(hpF + tb);
      u16x4 hq;
#pragma unroll
      for (int v = 0; v < 4; ++v) {
        const float z  = sigm(b2f(zp4[v]) + aZ[nf][ef][v]);
        const float ph = tanh_f(b2f(hp4[v]) + aH[nf][ef][v]);
        float hf = (1.0f - z) * b2f(shv[v]) + z * ph;
        if (e == 0 || !ev) hf = 0.f;          // e_mask + pad rows
        hq[v] = f2b(hf);
      }
      *(u16x4*)(sHn + (size_t)ef * 4096 + (size_t)(wn * 64 + lp) * 8 + jo) = hq;
    }
  }
  __syncthreads();   // B1: sHn ready; all global SG reads drained -> safe to overwrite

  // hu^T = Urp-frag x hnew-frag (from LDS)
  f32x4 aU[2][4];
#pragma unroll
  for (int nf = 0; nf < 2; ++nf)
#pragma unroll
    for (int ef = 0; ef < 4; ++ef) { aU[nf][ef][0]=0.f; aU[nf][ef][1]=0.f; aU[nf][ef][2]=0.f; aU[nf][ef][3]=0.f; }
#pragma unroll
  for (int kc = 0; kc < 8; ++kc) {
    short8 u0 = *(const short8*)(Urp + ((size_t)(kc * 16 + wn * 2 + 0) * 64 + lane) * 8);
    short8 u1 = *(const short8*)(Urp + ((size_t)(kc * 16 + wn * 2 + 1) * 64 + lane) * 8);
#pragma unroll
    for (int ef = 0; ef < 4; ++ef) {
      short8 hb = *(const short8*)(sHn + (size_t)ef * 4096 + (size_t)(kc * 64 + lane) * 8);
      aU[0][ef] = mfma16(u0, hb, aU[0][ef]);
      aU[1][ef] = mfma16(u1, hb, aU[1][ef]);
    }
  }

  // h natural write (LDS frag -> 128B-contiguous row chunks)
  {
    const int r = tid >> 3;
    const int e = e0 + r;
    if (e < NE) {
#pragma unroll
      for (int it = 0; it < 4; ++it) {
        const int c = (tid & 7) * 8 + it * 64;
        const short8 val = *(const short8*)(sHn + (size_t)(r >> 4) * 4096 +
                           (size_t)(((c >> 5) * 64 + (r & 15) + 16 * ((c >> 3) & 3)) * 8));
        *(short8*)(HB + (size_t)e * 512 + c) = val;
      }
    }
  }
  __syncthreads();   // B2: all sHn reads (Ur GEMM + h write) done

  // stage hu into sHn (reuse)
#pragma unroll
  for (int nf = 0; nf < 2; ++nf) {
    const int lp = row0 + 16 * (nf * 2 + (kq >> 1));
    const int jo = 4 * (kq & 1);
#pragma unroll
    for (int ef = 0; ef < 4; ++ef) {
      u16x4 uq;
#pragma unroll
      for (int v = 0; v < 4; ++v) uq[v] = f2b(aU[nf][ef][v]);
      *(u16x4*)(sHn + (size_t)ef * 4096 + (size_t)(wn * 64 + lp) * 8 + jo) = uq;
    }
  }
  __syncthreads();   // B3: hu frag ready

  // hu natural write
  {
    const int r = tid >> 3;
    const int e = e0 + r;
    if (e < NE) {
#pragma unroll
      for (int it = 0; it < 4; ++it) {
        const int c = (tid & 7) * 8 + it * 64;
        const short8 val = *(const short8*)(sHn + (size_t)(r >> 4) * 4096 +
                           (size_t)(((c >> 5) * 64 + (r & 15) + 16 * ((c >> 3) & 3)) * 8));
        *(short8*)(HB + (size_t)e * 512 + 256 + c) = val;
      }
    }
  }
}

// ---------------- depth-0: hn = sigm(zpre)*tanh(hpre); hu = hn @ Ur ----------------
// reads zpF/hpF frag tiles; writes natural h/hu (same LDS-transpose path)
__global__ __launch_bounds__(512, 4)
void step0(u16* __restrict__ HB, const u16* __restrict__ zpF, const u16* __restrict__ hpF,
           const u16* __restrict__ Urp) {
  __shared__ __align__(16) u16 sHn[16384];
  const int tid = threadIdx.x;
  const int wn = tid >> 6, lane = tid & 63;
  const int row0 = lane & 15, kq = lane >> 4;
  const int e0 = blockIdx.x * 64;

#pragma unroll
  for (int nf = 0; nf < 2; ++nf) {
    const int lp = row0 + 16 * (nf * 2 + (kq >> 1));
    const int jo = 4 * (kq & 1);
    const int nc = wn * 2 + nf;
#pragma unroll
    for (int ef = 0; ef < 4; ++ef) {
      const int ev = (e0 + ef * 16) < NE;
      const int e  = e0 + ef * 16 + row0;
      const size_t tb = ((size_t)((e0 >> 4) + ef) * 16 + nc) * 256 + lane * 4;
      const u16x4 zp4 = *(const u16x4*)(zpF + tb);
      const u16x4 hp4 = *(const u16x4*)(hpF + tb);
      u16x4 hq;
#pragma unroll
      for (int v = 0; v < 4; ++v) {
        float hf = sigm(b2f(zp4[v])) * tanh_f(b2f(hp4[v]));
        if (e == 0 || !ev) hf = 0.f;
        hq[v] = f2b(hf);
      }
      *(u16x4*)(sHn + (size_t)ef * 4096 + (size_t)(wn * 64 + lp) * 8 + jo) = hq;
    }
  }
  __syncthreads();

  f32x4 aU[2][4];
#pragma unroll
  for (int nf = 0; nf < 2; ++nf)
#pragma unroll
    for (int ef = 0; ef < 4; ++ef) { aU[nf][ef][0]=0.f; aU[nf][ef][1]=0.f; aU[nf][ef][2]=0.f; aU[nf][ef][3]=0.f; }
#pragma unroll
  for (int kc = 0; kc < 8; ++kc) {
    short8 u0 = *(const short8*)(Urp + ((size_t)(kc * 16 + wn * 2 + 0) * 64 + lane) * 8);
    short8 u1 = *(const short8*)(Urp + ((size_t)(kc * 16 + wn * 2 + 1) * 64 + lane) * 8);
#pragma unroll
    for (int ef = 0; ef < 4; ++ef) {
      short8 hb = *(const short8*)(sHn + (size_t)ef * 4096 + (size_t)(kc * 64 + lane) * 8);
      aU[0][ef] = mfma16(u0, hb, aU[0][ef]);
      aU[1][ef] = mfma16(u1, hb, aU[1][ef]);
    }
  }
  {
    const int r = tid >> 3;
    const int e = e0 + r;
    if (e < NE) {
#pragma unroll
      for (int it = 0; it < 4; ++it) {
        const int c = (tid & 7) * 8 + it * 64;
        const short8 val = *(const short8*)(sHn + (size_t)(r >> 4) * 4096 +
                           (size_t)(((c >> 5) * 64 + (r & 15) + 16 * ((c >> 3) & 3)) * 8));
        *(short8*)(HB + (size_t)e * 512 + c) = val;
      }
    }
  }
  __syncthreads();
#pragma unroll
  for (int nf = 0; nf < 2; ++nf) {
    const int lp = row0 + 16 * (nf * 2 + (kq >> 1));
    const int jo = 4 * (kq & 1);
#pragma unroll
    for (int ef = 0; ef < 4; ++ef) {
      u16x4 uq;
#pragma unroll
      for (int v = 0; v < 4; ++v) uq[v] = f2b(aU[nf][ef][v]);
      *(u16x4*)(sHn + (size_t)ef * 4096 + (size_t)(wn * 64 + lp) * 8 + jo) = uq;
    }
  }
  __syncthreads();
  {
    const int r = tid >> 3;
    const int e = e0 + r;
    if (e < NE) {
#pragma unroll
      for (int it = 0; it < 4; ++it) {
        const int c = (tid & 7) * 8 + it * 64;
        const short8 val = *(const short8*)(sHn + (size_t)(r >> 4) * 4096 +
                           (size_t)(((c >> 5) * 64 + (r & 15) + 16 * ((c >> 3) & 3)) * 8));
        *(short8*)(HB + (size_t)e * 512 + 256 + c) = val;
      }
    }
  }
}

// ---------------- readout ----------------
__global__ __launch_bounds__(256)
void readout(const u16* __restrict__ HB, const u16* __restrict__ fnp,
             const int* __restrict__ agraph, const u16* __restrict__ Wop,
             const float* __restrict__ bo, float* __restrict__ out) {
  __shared__ __align__(16) u16 sN[32][264];
  const int tid = threadIdx.x, wave = tid >> 6, lane = tid & 63;
  const int n0 = blockIdx.x * 32;
  const int row0 = lane & 15, kq = lane >> 4;

#pragma unroll 2
  for (int rr = 0; rr < 8; ++rr) {
    const int r = wave * 8 + rr;
    const int n = n0 + r;
    float s4[4] = {0.f, 0.f, 0.f, 0.f};
    if (n < NN) {
#pragma unroll
      for (int k = 0; k < 6; ++k) {
        const int idx = agraph[n * 6 + k];
        const u16x4 hv = *(const u16x4*)(HB + (size_t)idx * 512 + 4 * lane);
#pragma unroll
        for (int j = 0; j < 4; ++j) s4[j] += b2f(hv[j]);
      }
    }
#pragma unroll
    for (int j = 0; j < 4; ++j) sN[r][4 * lane + j] = f2b(s4[j]);
  }
  __syncthreads();

  f32x4 acc[2][4];
#pragma unroll
  for (int i = 0; i < 2; ++i)
#pragma unroll
    for (int n = 0; n < 4; ++n) { acc[i][n][0]=0.f; acc[i][n][1]=0.f; acc[i][n][2]=0.f; acc[i][n][3]=0.f; }
  const int ra = min(n0 + row0, NN - 1);
  const int rb = min(n0 + 16 + row0, NN - 1);
#pragma unroll
  for (int s = 0; s < 12; ++s) {
    short8 a0, a1;
    if (s < 4) {
      a0 = *(const short8*)(fnp + (size_t)ra * 128 + s * 32 + kq * 8);
      a1 = *(const short8*)(fnp + (size_t)rb * 128 + s * 32 + kq * 8);
    } else {
      a0 = *(const short8*)&sN[row0][(s - 4) * 32 + kq * 8];
      a1 = *(const short8*)&sN[row0 + 16][(s - 4) * 32 + kq * 8];
    }
#pragma unroll
    for (int ni = 0; ni < 4; ++ni) {
      short8 b = *(const short8*)(Wop + ((size_t)(s * 16 + wave * 4 + ni) * 64 + lane) * 8);
      acc[0][ni] = mfma16(a0, b, acc[0][ni]);
      acc[1][ni] = mfma16(a1, b, acc[1][ni]);
    }
  }
#pragma unroll
  for (int mi = 0; mi < 2; ++mi)
#pragma unroll
    for (int ni = 0; ni < 4; ++ni)
#pragma unroll
      for (int v = 0; v < 4; ++v) {
        const int m = mi * 16 + kq * 4 + v;
        const int col = wave * 64 + ni * 16 + row0;
        const int n = n0 + m;
        if (n < NN) {
          float val = fmaxf(acc[mi][ni][v] + bo[col], 0.f);
          if (n == 0) val = 0.f;             // n_mask
          out[(size_t)n * 256 + col] = val;
        }
      }
}

extern "C" void kernel_launch(void* const* d_in, const int* in_sizes, int n_in,
                              void* d_out, int out_size, void* d_ws, size_t ws_size,
                              hipStream_t stream) {
  const float* fnode      = (const float*)d_in[0];
  const int*   fmess_idx  = (const int*)d_in[1];
  const float* fmess_feat = (const float*)d_in[2];
  const int*   agraph     = (const int*)d_in[3];
  const int*   bgraph     = (const int*)d_in[4];
  const float* Wz         = (const float*)d_in[5];
  const float* bz         = (const float*)d_in[6];
  const float* Wr         = (const float*)d_in[7];
  const float* Ur         = (const float*)d_in[8];
  const float* bur        = (const float*)d_in[9];
  const float* Wh         = (const float*)d_in[10];
  const float* bh         = (const float*)d_in[11];
  const float* Wo         = (const float*)d_in[12];
  const float* bo         = (const float*)d_in[13];
  float* out = (float*)d_out;

  char* ws = (char*)d_ws;
  size_t off = 0;
  auto carve = [&](size_t bytes) -> char* {
    char* p = ws + off;
    off += (bytes + 511) & ~(size_t)511;
    return p;
  };
  u16* HB0  = (u16*)carve((size_t)NEP * 512 * 2);
  u16* HB1  = (u16*)carve((size_t)NEP * 512 * 2);
  u16* r1b  = (u16*)carve((size_t)NEP * 256 * 2);
  u16* zpF  = (u16*)carve((size_t)NEP * 256 * 2);
  u16* hpF  = (u16*)carve((size_t)NEP * 256 * 2);
  u16* hmF  = (u16*)carve((size_t)NEP * 128 * 2);
  u16* fnp  = (u16*)carve((size_t)NN * 128 * 2);
  u16* wpre = (u16*)carve((size_t)3 * 98304 * 2);
  u16* wgate= (u16*)carve((size_t)3 * 131072 * 2);
  u16* urp  = (u16*)carve((size_t)3 * 65536 * 2);
  u16* wop  = (u16*)carve((size_t)3 * 98304 * 2);
  if (off > ws_size) return;

  pack_wpre <<<dim3(384, 3), 256, 0, stream>>>(Wr, Wz, Wh, wpre);
  pack_wgate<<<dim3(512, 3), 256, 0, stream>>>(Wz, Wh, wgate);
  pack_ur   <<<dim3(256, 3), 256, 0, stream>>>(Ur, urp);
  pack_wo   <<<dim3(384, 3), 256, 0, stream>>>(Wo, wop);
  embed_hmess_f<<<NE / 2, 256, 0, stream>>>(fnode, fmess_idx, fmess_feat, hmF);
  embed_fnode<<<NN / 2, 256, 0, stream>>>(fnode, fnp);

  for (int g = 0; g < 3; ++g) {
    pre_gemm_t<<<dim3(NEP / 32, 3), 256, 0, stream>>>(
        hmF, wpre + (size_t)g * 98304, bur + g * 256, bz + g * 256, bh + g * 256,
        r1b, zpF, hpF);
    const u16* wgate_g = wgate + (size_t)g * 131072;
    const u16* urp_g   = urp + (size_t)g * 65536;
    step0<<<NEP / 64, 512, 0, stream>>>(HB0, zpF, hpF, urp_g);
    u16* bufs[2] = {HB0, HB1};
    int cur = 0;
    for (int d = 1; d < 6; ++d) {
      gather_sums<<<NE / 16, 512, 0, stream>>>(bufs[cur], bufs[1 - cur], r1b, bgraph);
      gru_step<<<NEP / 64, 512, 0, stream>>>(bufs[1 - cur], zpF, hpF, wgate_g, urp_g);
      cur ^= 1;
    }
    readout<<<(NN + 31) / 32, 256, 0, stream>>>(
        bufs[cur], fnp, agraph, wop + (size_t)g * 98304, bo + g * 256, out + (size_t)g * NN * 256);
  }
}

// Round 8
// 3306.142 us; speedup vs baseline: 1.9498x; 1.3464x over previous
//
#include <hip/hip_runtime.h>

// D-MPNN (chemprop) x3 encoders on MI355X.
// Algebra: h_nei@Ur == (h@Ur)[bgraph]; hmess@W hoisted (r1b/zpre/hpre).
// R7: fuse gather into gru (mpn_fused). Sums staged in LDS frag (64KB),
//     SG global intermediate deleted (-204 MB/step). HB natural both sides.

#define NE 100000   // messages
#define NEP 100032  // padded to 64-row blocks
#define NN 50000    // nodes

typedef unsigned short u16;
typedef short short8 __attribute__((ext_vector_type(8)));
typedef float f32x4 __attribute__((ext_vector_type(4)));
typedef unsigned short u16x4 __attribute__((ext_vector_type(4)));

__device__ __forceinline__ float b2f(u16 u) {
  union { unsigned int i; float f; } v; v.i = ((unsigned int)u) << 16; return v.f;
}
__device__ __forceinline__ u16 f2b(float f) {
  union { float f; unsigned int i; } v; v.f = f;
  unsigned int b = v.i;
  b += 0x7FFFu + ((b >> 16) & 1u);   // RTNE
  return (u16)(b >> 16);
}
__device__ __forceinline__ float sigm(float x) { return 1.0f / (1.0f + __expf(-x)); }
__device__ __forceinline__ float tanh_f(float x) { return 2.0f / (1.0f + __expf(-2.0f * x)) - 1.0f; }
__device__ __forceinline__ f32x4 mfma16(short8 a, short8 b, f32x4 c) {
  return __builtin_amdgcn_mfma_f32_16x16x32_bf16(a, b, c, 0, 0, 0);
}

// ---------------- weight packing (fragment-major) ----------------
__global__ void pack_wpre(const float* __restrict__ Wr, const float* __restrict__ Wz,
                          const float* __restrict__ Wh, u16* __restrict__ dst) {
  const int g = blockIdx.y;
  const int p = blockIdx.x * 256 + threadIdx.x;           // < 98304  (K=128,N=768)
  const int j = p & 7, l = (p >> 3) & 63, q = p >> 9;
  const int nb = q % 48, s = q / 48;
  const int k = 32 * s + 8 * (l >> 4) + j;
  const int n = 16 * nb + (l & 15);
  float v = 0.f;
  if (k < 104) {
    if (n < 256)      v = Wr[((size_t)g * 104 + k) * 256 + n];
    else if (n < 512) v = Wz[((size_t)g * 360 + k) * 256 + (n - 256)];
    else              v = Wh[((size_t)g * 360 + k) * 256 + (n - 512)];
  }
  dst[(size_t)g * 98304 + p] = f2b(v);
}

__global__ void pack_wgate(const float* __restrict__ Wz, const float* __restrict__ Wh,
                           u16* __restrict__ dst) {
  const int g = blockIdx.y;
  const int p = blockIdx.x * 256 + threadIdx.x;           // < 131072 (K=256,N=512)
  const int j = p & 7, l = (p >> 3) & 63, q = p >> 9;
  const int nb = q % 32, s = q / 32;
  const int k = 32 * s + 8 * (l >> 4) + j;
  const int n = 16 * nb + (l & 15);
  float v = (n < 256) ? Wz[((size_t)g * 360 + 104 + k) * 256 + n]
                      : Wh[((size_t)g * 360 + 104 + k) * 256 + (n - 256)];
  dst[(size_t)g * 131072 + p] = f2b(v);
}

__global__ void pack_ur(const float* __restrict__ Ur, u16* __restrict__ dst) {
  const int g = blockIdx.y;
  const int p = blockIdx.x * 256 + threadIdx.x;           // < 65536 (K=256,N=256)
  const int j = p & 7, l = (p >> 3) & 63, q = p >> 9;
  const int nb = q % 16, s = q / 16;
  const int k = 32 * s + 8 * (l >> 4) + j;
  const int n = 16 * nb + (l & 15);
  dst[(size_t)g * 65536 + p] = f2b(Ur[((size_t)g * 256 + k) * 256 + n]);
}

__global__ void pack_wo(const float* __restrict__ Wo, u16* __restrict__ dst) {
  const int g = blockIdx.y;
  const int p = blockIdx.x * 256 + threadIdx.x;           // < 98304 (K=384,N=256)
  const int j = p & 7, l = (p >> 3) & 63, q = p >> 9;
  const int nb = q % 16, s = q / 16;
  const int k = 32 * s + 8 * (l >> 4) + j;
  const int n = 16 * nb + (l & 15);
  float v = 0.f;
  if (k < 98)        v = Wo[((size_t)g * 354 + k) * 256 + n];        // fnode part
  else if (k >= 128) v = Wo[((size_t)g * 354 + (k - 30)) * 256 + n]; // nei part
  dst[(size_t)g * 98304 + p] = f2b(v);
}

// ---------------- embeddings ----------------
__global__ void embed_hmess_f(const float* __restrict__ fnode, const int* __restrict__ fmess_idx,
                              const float* __restrict__ fmess_feat, u16* __restrict__ hmF) {
  const int e = blockIdx.x * 2 + (threadIdx.x >> 7);
  const int c = threadIdx.x & 127;
  const int src = fmess_idx[e * 2];
  float v = 0.f;
  if (c < 98)       v = fnode[(size_t)src * 98 + c];
  else if (c < 104) v = fmess_feat[(size_t)e * 6 + (c - 98)];
  hmF[(size_t)(e >> 4) * 2048 + ((c >> 5) * 64 + (e & 15) + 16 * ((c >> 3) & 3)) * 8 + (c & 7)] = f2b(v);
}

__global__ void embed_fnode(const float* __restrict__ fnode, u16* __restrict__ fnp) {
  const int n = blockIdx.x * 2 + (threadIdx.x >> 7);
  const int c = threadIdx.x & 127;
  float v = (c < 98) ? fnode[(size_t)n * 98 + c] : 0.f;
  fnp[(size_t)n * 128 + c] = f2b(v);
}

// ---------------- pre-GEMM (transposed): r1b natural; zpre/hpre in D-frag tiles ----
__global__ __launch_bounds__(256)
void pre_gemm_t(const u16* __restrict__ hmF, const u16* __restrict__ Wpre,
                const float* __restrict__ bur, const float* __restrict__ bz,
                const float* __restrict__ bh, u16* __restrict__ r1b,
                u16* __restrict__ zpF, u16* __restrict__ hpF) {
  const int tid = threadIdx.x, wave = tid >> 6, lane = tid & 63;
  const int row0 = lane & 15, kq = lane >> 4;
  const int e0 = blockIdx.x * 32;
  const int cchunk = blockIdx.y;
  f32x4 acc[2][4];
#pragma unroll
  for (int i = 0; i < 2; ++i)
#pragma unroll
    for (int n = 0; n < 4; ++n) { acc[i][n][0]=0.f; acc[i][n][1]=0.f; acc[i][n][2]=0.f; acc[i][n][3]=0.f; }
#pragma unroll
  for (int kc = 0; kc < 4; ++kc) {
    short8 bf[2];
#pragma unroll
    for (int ef = 0; ef < 2; ++ef)
      bf[ef] = *(const short8*)(hmF + (size_t)((e0 >> 4) + ef) * 2048 + (size_t)(kc * 64 + lane) * 8);
#pragma unroll
    for (int nf = 0; nf < 4; ++nf) {
      const int nb = cchunk * 16 + wave * 4 + nf;
      short8 wf = *(const short8*)(Wpre + ((size_t)(kc * 48 + nb) * 64 + lane) * 8);
      acc[0][nf] = mfma16(wf, bf[0], acc[0][nf]);
      acc[1][nf] = mfma16(wf, bf[1], acc[1][nf]);
    }
  }
  const float* bias = (cchunk == 0) ? bur : (cchunk == 1 ? bz : bh);
  u16* dstF = (cchunk == 1) ? zpF : hpF;
#pragma unroll
  for (int ef = 0; ef < 2; ++ef)
#pragma unroll
    for (int nf = 0; nf < 4; ++nf) {
      const int n256 = wave * 64 + nf * 16 + kq * 4;
      const int e = e0 + ef * 16 + row0;
      u16x4 o;
#pragma unroll
      for (int v = 0; v < 4; ++v) o[v] = f2b(acc[ef][nf][v] + bias[n256 + v]);
      if (cchunk == 0) {
        *(u16x4*)(r1b + (size_t)e * 256 + n256) = o;
      } else {
        *(u16x4*)(dstF + ((size_t)((e0 >> 4) + ef) * 16 + (wave * 4 + nf)) * 256 + lane * 4) = o;
      }
    }
}

// ---------------- fused depth step: gather + gate GEMM + GRU + Ur GEMM ----------------
// HBin/HBout natural [e][512] (h | hu).  sF: sh frag [0,16384) u16, sg frag [16384,32768).
// sg region reused for hnew frag; sh region reused for hu frag.
__global__ __launch_bounds__(512, 4)
void mpn_fused(const u16* __restrict__ HBin, u16* __restrict__ HBout,
               const u16* __restrict__ r1b, const int* __restrict__ bgraph,
               const u16* __restrict__ zpF, const u16* __restrict__ hpF,
               const u16* __restrict__ Wgate, const u16* __restrict__ Urp) {
  __shared__ __align__(16) u16 sF[32768];   // 64 KB
  const int tid = threadIdx.x;
  const int wn = tid >> 6, lane = tid & 63;
  const int row0 = lane & 15, kq = lane >> 4;
  const int e0 = blockIdx.x * 64;

  // ---- gather: rows e0 + wn*8 .. +8; sums -> sF frag ----
  const int c0 = 4 * lane;
  const int offc = ((c0 >> 5) * 64 + 16 * ((c0 >> 3) & 3)) * 8 + (c0 & 7);
#pragma unroll 2
  for (int rr = 0; rr < 8; ++rr) {
    const int r = wn * 8 + rr;
    const int e = e0 + r;
    float sh[4] = {0.f, 0.f, 0.f, 0.f}, sg[4] = {0.f, 0.f, 0.f, 0.f};
    if (e < NE) {
      const u16x4 r1v = *(const u16x4*)(r1b + (size_t)e * 256 + c0);
      int idx[6];
#pragma unroll
      for (int k = 0; k < 6; ++k) idx[k] = bgraph[e * 6 + k];
      u16x4 hv[6], huv[6];
#pragma unroll
      for (int k = 0; k < 6; ++k) {
        const u16* rowp = HBin + (size_t)idx[k] * 512;
        hv[k]  = *(const u16x4*)(rowp + c0);
        huv[k] = *(const u16x4*)(rowp + 256 + c0);
      }
#pragma unroll
      for (int k = 0; k < 6; ++k)
#pragma unroll
        for (int j = 0; j < 4; ++j) {
          const float h  = b2f(hv[k][j]);
          const float rg = sigm(b2f(r1v[j]) + b2f(huv[k][j]));
          sh[j] += h;
          sg[j] += rg * h;
        }
    }
    u16x4 o0, o1;
#pragma unroll
    for (int j = 0; j < 4; ++j) { o0[j] = f2b(sh[j]); o1[j] = f2b(sg[j]); }
    const int off = (r >> 4) * 4096 + offc + (r & 15) * 8;
    *(u16x4*)(sF + off) = o0;
    *(u16x4*)(sF + 16384 + off) = o1;
  }
  __syncthreads();   // B0: sF ready

  // ---- gate GEMMs: gz^T = Wz2 x sh, gh^T = Wh2 x sg (frags from LDS) ----
  f32x4 aZ[2][4], aH[2][4];
#pragma unroll
  for (int nf = 0; nf < 2; ++nf)
#pragma unroll
    for (int ef = 0; ef < 4; ++ef) {
      aZ[nf][ef][0]=0.f; aZ[nf][ef][1]=0.f; aZ[nf][ef][2]=0.f; aZ[nf][ef][3]=0.f;
      aH[nf][ef][0]=0.f; aH[nf][ef][1]=0.f; aH[nf][ef][2]=0.f; aH[nf][ef][3]=0.f;
    }
#pragma unroll
  for (int kc = 0; kc < 8; ++kc) {
    short8 wz0 = *(const short8*)(Wgate + ((size_t)(kc * 32 + wn * 2 + 0) * 64 + lane) * 8);
    short8 wz1 = *(const short8*)(Wgate + ((size_t)(kc * 32 + wn * 2 + 1) * 64 + lane) * 8);
    short8 wh0 = *(const short8*)(Wgate + ((size_t)(kc * 32 + 16 + wn * 2 + 0) * 64 + lane) * 8);
    short8 wh1 = *(const short8*)(Wgate + ((size_t)(kc * 32 + 16 + wn * 2 + 1) * 64 + lane) * 8);
#pragma unroll
    for (int ef = 0; ef < 4; ++ef) {
      short8 bsh = *(const short8*)(sF + ef * 4096 + (kc * 64 + lane) * 8);
      short8 bsg = *(const short8*)(sF + 16384 + ef * 4096 + (kc * 64 + lane) * 8);
      aZ[0][ef] = mfma16(wz0, bsh, aZ[0][ef]);
      aZ[1][ef] = mfma16(wz1, bsh, aZ[1][ef]);
      aH[0][ef] = mfma16(wh0, bsg, aH[0][ef]);
      aH[1][ef] = mfma16(wh1, bsg, aH[1][ef]);
    }
  }

  // ---- GRU epilogue into registers (shv from sF, zp/hp frag-coalesced global) ----
  u16x4 hq[2][4];
#pragma unroll
  for (int nf = 0; nf < 2; ++nf) {
    const int lp = row0 + 16 * (nf * 2 + (kq >> 1));
    const int jo = 4 * (kq & 1);
    const int nc = wn * 2 + nf;
#pragma unroll
    for (int ef = 0; ef < 4; ++ef) {
      const int ev = (e0 + ef * 16) < NE;
      const int e  = e0 + ef * 16 + row0;
      const u16x4 shv = *(const u16x4*)(sF + ef * 4096 + (wn * 64 + lp) * 8 + jo);
      const size_t tb = ((size_t)((e0 >> 4) + ef) * 16 + nc) * 256 + lane * 4;
      const u16x4 zp4 = *(const u16x4*)(zpF + tb);
      const u16x4 hp4 = *(const u16x4*)(hpF + tb);
#pragma unroll
      for (int v = 0; v < 4; ++v) {
        const float z  = sigm(b2f(zp4[v]) + aZ[nf][ef][v]);
        const float ph = tanh_f(b2f(hp4[v]) + aH[nf][ef][v]);
        float hf = (1.0f - z) * b2f(shv[v]) + z * ph;
        if (e == 0 || !ev) hf = 0.f;          // e_mask + pad rows
        hq[nf][ef][v] = f2b(hf);
      }
    }
  }
  __syncthreads();   // B1: all sF (sh+sg) reads done -> safe to overwrite sg region

  // hnew frag into sg region
#pragma unroll
  for (int nf = 0; nf < 2; ++nf) {
    const int lp = row0 + 16 * (nf * 2 + (kq >> 1));
    const int jo = 4 * (kq & 1);
#pragma unroll
    for (int ef = 0; ef < 4; ++ef)
      *(u16x4*)(sF + 16384 + ef * 4096 + (wn * 64 + lp) * 8 + jo) = hq[nf][ef];
  }
  __syncthreads();   // B2: hnew frag ready

  // ---- hu^T = Urp x hnew (frag from LDS) ----
  f32x4 aU[2][4];
#pragma unroll
  for (int nf = 0; nf < 2; ++nf)
#pragma unroll
    for (int ef = 0; ef < 4; ++ef) { aU[nf][ef][0]=0.f; aU[nf][ef][1]=0.f; aU[nf][ef][2]=0.f; aU[nf][ef][3]=0.f; }
#pragma unroll
  for (int kc = 0; kc < 8; ++kc) {
    short8 u0 = *(const short8*)(Urp + ((size_t)(kc * 16 + wn * 2 + 0) * 64 + lane) * 8);
    short8 u1 = *(const short8*)(Urp + ((size_t)(kc * 16 + wn * 2 + 1) * 64 + lane) * 8);
#pragma unroll
    for (int ef = 0; ef < 4; ++ef) {
      short8 hb = *(const short8*)(sF + 16384 + ef * 4096 + (kc * 64 + lane) * 8);
      aU[0][ef] = mfma16(u0, hb, aU[0][ef]);
      aU[1][ef] = mfma16(u1, hb, aU[1][ef]);
    }
  }

  // h natural write (sg-region frag -> coalesced rows)
  {
    const int r = tid >> 3;
    const int e = e0 + r;
    if (e < NE) {
#pragma unroll
      for (int it = 0; it < 4; ++it) {
        const int c = (tid & 7) * 8 + it * 64;
        const short8 val = *(const short8*)(sF + 16384 + (r >> 4) * 4096 +
                           (((c >> 5) * 64 + (r & 15) + 16 * ((c >> 3) & 3)) * 8));
        *(short8*)(HBout + (size_t)e * 512 + c) = val;
      }
    }
  }
  // stage hu into sh region (dead since B1)
#pragma unroll
  for (int nf = 0; nf < 2; ++nf) {
    const int lp = row0 + 16 * (nf * 2 + (kq >> 1));
    const int jo = 4 * (kq & 1);
#pragma unroll
    for (int ef = 0; ef < 4; ++ef) {
      u16x4 uq;
#pragma unroll
      for (int v = 0; v < 4; ++v) uq[v] = f2b(aU[nf][ef][v]);
      *(u16x4*)(sF + ef * 4096 + (wn * 64 + lp) * 8 + jo) = uq;
    }
  }
  __syncthreads();   // B3: hu frag ready

  // hu natural write
  {
    const int r = tid >> 3;
    const int e = e0 + r;
    if (e < NE) {
#pragma unroll
      for (int it = 0; it < 4; ++it) {
        const int c = (tid & 7) * 8 + it * 64;
        const short8 val = *(const short8*)(sF + (r >> 4) * 4096 +
                           (((c >> 5) * 64 + (r & 15) + 16 * ((c >> 3) & 3)) * 8));
        *(short8*)(HBout + (size_t)e * 512 + 256 + c) = val;
      }
    }
  }
}

// ---------------- depth-0: hn = sigm(zpre)*tanh(hpre); hu = hn @ Ur ----------------
__global__ __launch_bounds__(512, 4)
void step0(u16* __restrict__ HB, const u16* __restrict__ zpF, const u16* __restrict__ hpF,
           const u16* __restrict__ Urp) {
  __shared__ __align__(16) u16 sHn[16384];
  const int tid = threadIdx.x;
  const int wn = tid >> 6, lane = tid & 63;
  const int row0 = lane & 15, kq = lane >> 4;
  const int e0 = blockIdx.x * 64;

#pragma unroll
  for (int nf = 0; nf < 2; ++nf) {
    const int lp = row0 + 16 * (nf * 2 + (kq >> 1));
    const int jo = 4 * (kq & 1);
    const int nc = wn * 2 + nf;
#pragma unroll
    for (int ef = 0; ef < 4; ++ef) {
      const int ev = (e0 + ef * 16) < NE;
      const int e  = e0 + ef * 16 + row0;
      const size_t tb = ((size_t)((e0 >> 4) + ef) * 16 + nc) * 256 + lane * 4;
      const u16x4 zp4 = *(const u16x4*)(zpF + tb);
      const u16x4 hp4 = *(const u16x4*)(hpF + tb);
      u16x4 hq;
#pragma unroll
      for (int v = 0; v < 4; ++v) {
        float hf = sigm(b2f(zp4[v])) * tanh_f(b2f(hp4[v]));
        if (e == 0 || !ev) hf = 0.f;
        hq[v] = f2b(hf);
      }
      *(u16x4*)(sHn + (size_t)ef * 4096 + (size_t)(wn * 64 + lp) * 8 + jo) = hq;
    }
  }
  __syncthreads();

  f32x4 aU[2][4];
#pragma unroll
  for (int nf = 0; nf < 2; ++nf)
#pragma unroll
    for (int ef = 0; ef < 4; ++ef) { aU[nf][ef][0]=0.f; aU[nf][ef][1]=0.f; aU[nf][ef][2]=0.f; aU[nf][ef][3]=0.f; }
#pragma unroll
  for (int kc = 0; kc < 8; ++kc) {
    short8 u0 = *(const short8*)(Urp + ((size_t)(kc * 16 + wn * 2 + 0) * 64 + lane) * 8);
    short8 u1 = *(const short8*)(Urp + ((size_t)(kc * 16 + wn * 2 + 1) * 64 + lane) * 8);
#pragma unroll
    for (int ef = 0; ef < 4; ++ef) {
      short8 hb = *(const short8*)(sHn + (size_t)ef * 4096 + (size_t)(kc * 64 + lane) * 8);
      aU[0][ef] = mfma16(u0, hb, aU[0][ef]);
      aU[1][ef] = mfma16(u1, hb, aU[1][ef]);
    }
  }
  {
    const int r = tid >> 3;
    const int e = e0 + r;
    if (e < NE) {
#pragma unroll
      for (int it = 0; it < 4; ++it) {
        const int c = (tid & 7) * 8 + it * 64;
        const short8 val = *(const short8*)(sHn + (size_t)(r >> 4) * 4096 +
                           (size_t)(((c >> 5) * 64 + (r & 15) + 16 * ((c >> 3) & 3)) * 8));
        *(short8*)(HB + (size_t)e * 512 + c) = val;
      }
    }
  }
  __syncthreads();
#pragma unroll
  for (int nf = 0; nf < 2; ++nf) {
    const int lp = row0 + 16 * (nf * 2 + (kq >> 1));
    const int jo = 4 * (kq & 1);
#pragma unroll
    for (int ef = 0; ef < 4; ++ef) {
      u16x4 uq;
#pragma unroll
      for (int v = 0; v < 4; ++v) uq[v] = f2b(aU[nf][ef][v]);
      *(u16x4*)(sHn + (size_t)ef * 4096 + (size_t)(wn * 64 + lp) * 8 + jo) = uq;
    }
  }
  __syncthreads();
  {
    const int r = tid >> 3;
    const int e = e0 + r;
    if (e < NE) {
#pragma unroll
      for (int it = 0; it < 4; ++it) {
        const int c = (tid & 7) * 8 + it * 64;
        const short8 val = *(const short8*)(sHn + (size_t)(r >> 4) * 4096 +
                           (size_t)(((c >> 5) * 64 + (r & 15) + 16 * ((c >> 3) & 3)) * 8));
        *(short8*)(HB + (size_t)e * 512 + 256 + c) = val;
      }
    }
  }
}

// ---------------- readout ----------------
__global__ __launch_bounds__(256)
void readout(const u16* __restrict__ HB, const u16* __restrict__ fnp,
             const int* __restrict__ agraph, const u16* __restrict__ Wop,
             const float* __restrict__ bo, float* __restrict__ out) {
  __shared__ __align__(16) u16 sN[32][264];
  const int tid = threadIdx.x, wave = tid >> 6, lane = tid & 63;
  const int n0 = blockIdx.x * 32;
  const int row0 = lane & 15, kq = lane >> 4;

#pragma unroll 2
  for (int rr = 0; rr < 8; ++rr) {
    const int r = wave * 8 + rr;
    const int n = n0 + r;
    float s4[4] = {0.f, 0.f, 0.f, 0.f};
    if (n < NN) {
#pragma unroll
      for (int k = 0; k < 6; ++k) {
        const int idx = agraph[n * 6 + k];
        const u16x4 hv = *(const u16x4*)(HB + (size_t)idx * 512 + 4 * lane);
#pragma unroll
        for (int j = 0; j < 4; ++j) s4[j] += b2f(hv[j]);
      }
    }
#pragma unroll
    for (int j = 0; j < 4; ++j) sN[r][4 * lane + j] = f2b(s4[j]);
  }
  __syncthreads();

  f32x4 acc[2][4];
#pragma unroll
  for (int i = 0; i < 2; ++i)
#pragma unroll
    for (int n = 0; n < 4; ++n) { acc[i][n][0]=0.f; acc[i][n][1]=0.f; acc[i][n][2]=0.f; acc[i][n][3]=0.f; }
  const int ra = min(n0 + row0, NN - 1);
  const int rb = min(n0 + 16 + row0, NN - 1);
#pragma unroll
  for (int s = 0; s < 12; ++s) {
    short8 a0, a1;
    if (s < 4) {
      a0 = *(const short8*)(fnp + (size_t)ra * 128 + s * 32 + kq * 8);
      a1 = *(const short8*)(fnp + (size_t)rb * 128 + s * 32 + kq * 8);
    } else {
      a0 = *(const short8*)&sN[row0][(s - 4) * 32 + kq * 8];
      a1 = *(const short8*)&sN[row0 + 16][(s - 4) * 32 + kq * 8];
    }
#pragma unroll
    for (int ni = 0; ni < 4; ++ni) {
      short8 b = *(const short8*)(Wop + ((size_t)(s * 16 + wave * 4 + ni) * 64 + lane) * 8);
      acc[0][ni] = mfma16(a0, b, acc[0][ni]);
      acc[1][ni] = mfma16(a1, b, acc[1][ni]);
    }
  }
#pragma unroll
  for (int mi = 0; mi < 2; ++mi)
#pragma unroll
    for (int ni = 0; ni < 4; ++ni)
#pragma unroll
      for (int v = 0; v < 4; ++v) {
        const int m = mi * 16 + kq * 4 + v;
        const int col = wave * 64 + ni * 16 + row0;
        const int n = n0 + m;
        if (n < NN) {
          float val = fmaxf(acc[mi][ni][v] + bo[col], 0.f);
          if (n == 0) val = 0.f;             // n_mask
          out[(size_t)n * 256 + col] = val;
        }
      }
}

extern "C" void kernel_launch(void* const* d_in, const int* in_sizes, int n_in,
                              void* d_out, int out_size, void* d_ws, size_t ws_size,
                              hipStream_t stream) {
  const float* fnode      = (const float*)d_in[0];
  const int*   fmess_idx  = (const int*)d_in[1];
  const float* fmess_feat = (const float*)d_in[2];
  const int*   agraph     = (const int*)d_in[3];
  const int*   bgraph     = (const int*)d_in[4];
  const float* Wz         = (const float*)d_in[5];
  const float* bz         = (const float*)d_in[6];
  const float* Wr         = (const float*)d_in[7];
  const float* Ur         = (const float*)d_in[8];
  const float* bur        = (const float*)d_in[9];
  const float* Wh         = (const float*)d_in[10];
  const float* bh         = (const float*)d_in[11];
  const float* Wo         = (const float*)d_in[12];
  const float* bo         = (const float*)d_in[13];
  float* out = (float*)d_out;

  char* ws = (char*)d_ws;
  size_t off = 0;
  auto carve = [&](size_t bytes) -> char* {
    char* p = ws + off;
    off += (bytes + 511) & ~(size_t)511;
    return p;
  };
  u16* HB0  = (u16*)carve((size_t)NEP * 512 * 2);
  u16* HB1  = (u16*)carve((size_t)NEP * 512 * 2);
  u16* r1b  = (u16*)carve((size_t)NEP * 256 * 2);
  u16* zpF  = (u16*)carve((size_t)NEP * 256 * 2);
  u16* hpF  = (u16*)carve((size_t)NEP * 256 * 2);
  u16* hmF  = (u16*)carve((size_t)NEP * 128 * 2);
  u16* fnp  = (u16*)carve((size_t)NN * 128 * 2);
  u16* wpre = (u16*)carve((size_t)3 * 98304 * 2);
  u16* wgate= (u16*)carve((size_t)3 * 131072 * 2);
  u16* urp  = (u16*)carve((size_t)3 * 65536 * 2);
  u16* wop  = (u16*)carve((size_t)3 * 98304 * 2);
  if (off > ws_size) return;

  pack_wpre <<<dim3(384, 3), 256, 0, stream>>>(Wr, Wz, Wh, wpre);
  pack_wgate<<<dim3(512, 3), 256, 0, stream>>>(Wz, Wh, wgate);
  pack_ur   <<<dim3(256, 3), 256, 0, stream>>>(Ur, urp);
  pack_wo   <<<dim3(384, 3), 256, 0, stream>>>(Wo, wop);
  embed_hmess_f<<<NE / 2, 256, 0, stream>>>(fnode, fmess_idx, fmess_feat, hmF);
  embed_fnode<<<NN / 2, 256, 0, stream>>>(fnode, fnp);

  for (int g = 0; g < 3; ++g) {
    pre_gemm_t<<<dim3(NEP / 32, 3), 256, 0, stream>>>(
        hmF, wpre + (size_t)g * 98304, bur + g * 256, bz + g * 256, bh + g * 256,
        r1b, zpF, hpF);
    const u16* wgate_g = wgate + (size_t)g * 131072;
    const u16* urp_g   = urp + (size_t)g * 65536;
    step0<<<NEP / 64, 512, 0, stream>>>(HB0, zpF, hpF, urp_g);
    u16* bufs[2] = {HB0, HB1};
    int cur = 0;
    for (int d = 1; d < 6; ++d) {
      mpn_fused<<<NEP / 64, 512, 0, stream>>>(bufs[cur], bufs[1 - cur], r1b, bgraph,
                                              zpF, hpF, wgate_g, urp_g);
      cur ^= 1;
    }
    readout<<<(NN + 31) / 32, 256, 0, stream>>>(
        bufs[cur], fnp, agraph, wop + (size_t)g * 98304, bo + g * 256, out + (size_t)g * NN * 256);
  }
}